// Round 4
// baseline (2660.323 us; speedup 1.0000x reference)
//
#include <hip/hip_runtime.h>
#include <math.h>

// AKOrN layer — split-bf16 MFMA for init AND steps, DMA staging, swapped
// operand roles (A = data, B = stationary matrix) so MFMA C-columns are the
// oscillator index -> lane-contiguous epilogue stores.
//
// This revision:
//  * MFMA ILP fix: inner product issued as 3 passes of 16 INDEPENDENT MFMAs
//    (hh pass, lh pass, hl pass) instead of 16 chains of 3 dependent MFMAs.
//    Per-accumulator order unchanged (hh->lh->hl) -> bit-identical numerics.
//  * s_setprio(1) around the MFMA passes (waves are phase-split by the
//    prefetch, so priority arbitration has something to do).
//  * (kept) double-buffered LDS prefetch-1, XCD-aware block swizzle.
//
//   v0 = normalize_d(x @ W_in)            (split-bf16 MFMA)
//   K' = tanh(coupling) + I
//   8x: v = normalize_d(K' v + omega)     (split-bf16 MFMA)

#define B_SZ   8192
#define OUT_SZ 1024
#define STEPS  8
#define PLANE  ((size_t)B_SZ * OUT_SZ)
#define WPLANE ((size_t)OUT_SZ * OUT_SZ)

typedef __attribute__((ext_vector_type(8))) short  short8;
typedef __attribute__((ext_vector_type(4))) float  f32x4;
typedef unsigned short us;

__device__ __forceinline__ us f2bf(float f) {
    union { float f; unsigned u; } v; v.f = f;
    unsigned r = v.u + 0x7FFFu + ((v.u >> 16) & 1u);
    return (us)(r >> 16);
}
__device__ __forceinline__ float bf2f(us h) {
    union { unsigned u; float f; } v; v.u = ((unsigned)h) << 16;
    return v.f;
}
// async global->LDS, 16B per lane, dest = uniform base + lane*16
__device__ __forceinline__ void dma16(const void* g, void* l) {
    __builtin_amdgcn_global_load_lds(
        (const __attribute__((address_space(1))) void*)g,
        (__attribute__((address_space(3))) void*)l, 16, 0, 0);
}
__device__ __forceinline__ float rnorm4(float a, float b, float c, float d) {
    float n2 = a * a + b * b + c * c + d * d;
    float s = rsqrtf(fmaxf(n2, 1e-24f));
    return s * (1.5f - 0.5f * n2 * s * s);   // 1 NR step -> fp32 accuracy
}

// ------------------------------------------------ prep: K' = tanh(c)+I, split
__global__ void tanhsplit_kernel(const float* __restrict__ c,
                                 us* __restrict__ Khi, us* __restrict__ Klo) {
    int idx = blockIdx.x * 256 + threadIdx.x;
    float val = tanhf(c[idx]) + (((idx >> 10) == (idx & (OUT_SZ - 1))) ? 1.0f : 0.0f);
    us hi = f2bf(val);
    Khi[idx] = hi;
    Klo[idx] = f2bf(val - bf2f(hi));
}

// ------------------------------------------------ prep: split x -> bf16 hi/lo
__global__ void xsplit_kernel(const float* __restrict__ x,
                              us* __restrict__ Xhi, us* __restrict__ Xlo) {
    int idx = (blockIdx.x * 256 + threadIdx.x) * 4;
    float4 v = *(const float4*)&x[idx];
    float p[4] = { v.x, v.y, v.z, v.w };
    unsigned h01, h23, l01, l23;
    us h[4], l[4];
#pragma unroll
    for (int t = 0; t < 4; ++t) {
        h[t] = f2bf(p[t]);
        l[t] = f2bf(p[t] - bf2f(h[t]));
    }
    h01 = (unsigned)h[0] | ((unsigned)h[1] << 16);
    h23 = (unsigned)h[2] | ((unsigned)h[3] << 16);
    l01 = (unsigned)l[0] | ((unsigned)l[1] << 16);
    l23 = (unsigned)l[2] | ((unsigned)l[3] << 16);
    ((unsigned*)Xhi)[idx / 2]     = h01;
    ((unsigned*)Xhi)[idx / 2 + 1] = h23;
    ((unsigned*)Xlo)[idx / 2]     = l01;
    ((unsigned*)Xlo)[idx / 2 + 1] = l23;
}

// ------------------------------------------------ prep: W [k][o][d] -> Wt [d][o][k] split
__global__ void wprep_kernel(const float* __restrict__ W,
                             us* __restrict__ Wthi, us* __restrict__ Wtlo) {
    int idx = blockIdx.x * 256 + threadIdx.x;        // 262144 total
    int d  = idx & 3;
    int o  = (idx >> 2) & (OUT_SZ - 1);
    int kc = idx >> 12;                              // 0..63, 16 k each
    us h[16], l[16];
#pragma unroll
    for (int t = 0; t < 16; ++t) {
        float v = W[((size_t)(kc * 16 + t) * OUT_SZ + o) * 4 + d];
        h[t] = f2bf(v);
        l[t] = f2bf(v - bf2f(h[t]));
    }
    size_t base = (size_t)d * WPLANE + (size_t)o * OUT_SZ + kc * 16;
#pragma unroll
    for (int t = 0; t < 16; ++t) { Wthi[base + t] = h[t]; Wtlo[base + t] = l[t]; }
}

// ------------------------------------------------ step: v' = norm(K' v + w)
// A = v (m=b), B = K' (n=i).  Block 32 b x 128 i, 4 waves:
// wm = wv&1 -> 16-b half, wn = wv>>1 -> 64-i half (nf=0..3).
// LDS frag slots: 512 shorts (64 lanes x 16B), lane-linear (DMA-compatible).
// Double-buffered: stage(t+1) issued before compute(t); 1 barrier/iter.
__global__ __launch_bounds__(256, 2) void step_mfma_kernel(
    const us* __restrict__ Vhi, const us* __restrict__ Vlo,
    const us* __restrict__ Khi, const us* __restrict__ Klo,
    const float* __restrict__ omega,
    us* __restrict__ Ohi, us* __restrict__ Olo,
    float* __restrict__ out, int final_step)
{
    __shared__ short As[2][8192];   // v tile:  frag (d*2+bh)*2+hl
    __shared__ short Bs[2][8192];   // K' tile: frag ib*2+hl

    const int tid = threadIdx.x;
    const int ln = tid & 63, wv = tid >> 6;
    const int wm = wv & 1, wn = wv >> 1;

    // XCD swizzle: 2048 blocks, lid%8 = XCD. Remap so 8 consecutive work-ids
    // (same b0, all 8 i0 columns) land on ONE XCD -> V tile L2-resident.
    const int lid = blockIdx.y * 8 + blockIdx.x;          // 0..2047
    const int n   = (lid & 7) * 256 + (lid >> 3);         // bijective
    const int i0 = (n & 7) * 128;
    const int b0 = (n >> 3) * 32;

    // 8 DMA frags per wave: waves 0,1 -> A (16 frags), waves 2,3 -> B (16 frags)
    const us* gsrc[8];
    short*    ldst[8];
    if (wv < 2) {
        int t = 0;
#pragma unroll
        for (int dq = 0; dq < 2; ++dq)
#pragma unroll
            for (int bh = 0; bh < 2; ++bh)
#pragma unroll
                for (int hl = 0; hl < 2; ++hl) {
                    int d = wv * 2 + dq;
                    int b = b0 + bh * 16 + (ln & 15);
                    const us* base = hl ? Vlo : Vhi;
                    gsrc[t] = base + (size_t)d * PLANE + (size_t)b * OUT_SZ + (ln >> 4) * 8;
                    ldst[t] = &As[0][((d * 2 + bh) * 2 + hl) * 512];
                    ++t;
                }
    } else {
        int t = 0;
#pragma unroll
        for (int iq = 0; iq < 4; ++iq)
#pragma unroll
            for (int hl = 0; hl < 2; ++hl) {
                int ib = (wv - 2) * 4 + iq;
                int i = i0 + ib * 16 + (ln & 15);
                const us* base = hl ? Klo : Khi;
                gsrc[t] = base + (size_t)i * OUT_SZ + (ln >> 4) * 8;
                ldst[t] = &Bs[0][(ib * 2 + hl) * 512];
                ++t;
            }
    }

    f32x4 acc[4][4];   // [d][nf]
#pragma unroll
    for (int d = 0; d < 4; ++d)
#pragma unroll
        for (int nf = 0; nf < 4; ++nf) acc[d][nf] = (f32x4){0.f, 0.f, 0.f, 0.f};

    // prologue: stage tile 0 into buffer 0
#pragma unroll
    for (int t = 0; t < 8; ++t) { dma16(gsrc[t], ldst[t]); gsrc[t] += 32; }

    int cur = 0;
    for (int it = 0; it < 32; ++it) {
        __syncthreads();                       // buf[cur] staged; prev reads done
        if (it + 1 < 32) {                     // prefetch next tile into buf[cur^1]
#pragma unroll
            for (int t = 0; t < 8; ++t) {
                dma16(gsrc[t], ldst[t] + (cur ^ 1) * 8192);
                gsrc[t] += 32;
            }
        }

        short8 a[4][2], b[4][2];
#pragma unroll
        for (int d = 0; d < 4; ++d)
#pragma unroll
            for (int hl = 0; hl < 2; ++hl)
                a[d][hl] = *(const short8*)&As[cur][(((d * 2 + wm) * 2 + hl)) * 512 + ln * 8];
#pragma unroll
        for (int nf = 0; nf < 4; ++nf)
#pragma unroll
            for (int hl = 0; hl < 2; ++hl)
                b[nf][hl] = *(const short8*)&Bs[cur][((wn * 4 + nf) * 2 + hl) * 512 + ln * 8];

        // 3 passes x 16 independent MFMAs; per-acc order hh->lh->hl unchanged.
        __builtin_amdgcn_s_setprio(1);
#pragma unroll
        for (int d = 0; d < 4; ++d)
#pragma unroll
            for (int nf = 0; nf < 4; ++nf)
                acc[d][nf] = __builtin_amdgcn_mfma_f32_16x16x32_bf16(a[d][0], b[nf][0], acc[d][nf], 0, 0, 0);
#pragma unroll
        for (int d = 0; d < 4; ++d)
#pragma unroll
            for (int nf = 0; nf < 4; ++nf)
                acc[d][nf] = __builtin_amdgcn_mfma_f32_16x16x32_bf16(a[d][1], b[nf][0], acc[d][nf], 0, 0, 0);
#pragma unroll
        for (int d = 0; d < 4; ++d)
#pragma unroll
            for (int nf = 0; nf < 4; ++nf)
                acc[d][nf] = __builtin_amdgcn_mfma_f32_16x16x32_bf16(a[d][0], b[nf][1], acc[d][nf], 0, 0, 0);
        __builtin_amdgcn_s_setprio(0);
        cur ^= 1;
    }

    // epilogue: C row = b, col = i (lane-contiguous stores)
#pragma unroll
    for (int nf = 0; nf < 4; ++nf) {
        const int i = i0 + wn * 64 + nf * 16 + (ln & 15);
        const f32x4 om = *(const f32x4*)&omega[i * 4];
#pragma unroll
        for (int reg = 0; reg < 4; ++reg) {
            const int b = b0 + wm * 16 + (ln >> 4) * 4 + reg;
            float tv[4];
#pragma unroll
            for (int d = 0; d < 4; ++d) tv[d] = acc[d][nf][reg] + om[d];
            float s = rnorm4(tv[0], tv[1], tv[2], tv[3]);
            if (final_step) {
                f32x4 rr = { tv[0] * s, tv[1] * s, tv[2] * s, tv[3] * s };
                *(f32x4*)&out[((size_t)b * OUT_SZ + i) * 4] = rr;
            } else {
#pragma unroll
                for (int d = 0; d < 4; ++d) {
                    float val = tv[d] * s;
                    us hi = f2bf(val);
                    size_t idx = (size_t)d * PLANE + (size_t)b * OUT_SZ + i;
                    Ohi[idx] = hi;
                    Olo[idx] = f2bf(val - bf2f(hi));
                }
            }
        }
    }
}

// ------------------------------------------------ init: v0 = norm(x @ W)
// A = x (m=b, d-independent), B = Wt planes (n=o, per d).
// Block 128 b x 32 o, 4 waves: wm -> 64-b half (mf=0..3), wn -> 16-o half.
// Double-buffered + swizzled like the step kernel.
__global__ __launch_bounds__(256, 2) void init_mfma_kernel(
    const us* __restrict__ Xhi, const us* __restrict__ Xlo,
    const us* __restrict__ Wthi, const us* __restrict__ Wtlo,
    us* __restrict__ Ohi, us* __restrict__ Olo)
{
    __shared__ short As[2][8192];   // x tile:  frag bf*2+hl  (bf=0..7)
    __shared__ short Bs[2][8192];   // Wt tile: frag (d*2+oh)*2+hl

    const int tid = threadIdx.x;
    const int ln = tid & 63, wv = tid >> 6;
    const int wm = wv & 1, wn = wv >> 1;

    // swizzle: 8 consecutive work-ids (same o-tile group) per XCD -> Wt L2-reuse
    const int lid = blockIdx.y * 64 + blockIdx.x;         // 0..2047
    const int n   = (lid & 7) * 256 + (lid >> 3);         // bijective
    const int b0 = (n & 63) * 128;
    const int o0 = (n >> 6) * 32;

    const us* gsrc[8];
    short*    ldst[8];
    if (wv < 2) {
        int t = 0;
#pragma unroll
        for (int bq = 0; bq < 4; ++bq)
#pragma unroll
            for (int hl = 0; hl < 2; ++hl) {
                int bf = wv * 4 + bq;
                int b = b0 + bf * 16 + (ln & 15);
                const us* base = hl ? Xlo : Xhi;
                gsrc[t] = base + (size_t)b * 1024 + (ln >> 4) * 8;
                ldst[t] = &As[0][(bf * 2 + hl) * 512];
                ++t;
            }
    } else {
        int t = 0;
#pragma unroll
        for (int dq = 0; dq < 2; ++dq)
#pragma unroll
            for (int oh = 0; oh < 2; ++oh)
#pragma unroll
                for (int hl = 0; hl < 2; ++hl) {
                    int d = (wv - 2) * 2 + dq;
                    int o = o0 + oh * 16 + (ln & 15);
                    const us* base = hl ? Wtlo : Wthi;
                    gsrc[t] = base + (size_t)d * WPLANE + (size_t)o * OUT_SZ + (ln >> 4) * 8;
                    ldst[t] = &Bs[0][((d * 2 + oh) * 2 + hl) * 512];
                    ++t;
                }
    }

    f32x4 acc[4][4];   // [d][mf]
#pragma unroll
    for (int d = 0; d < 4; ++d)
#pragma unroll
        for (int mf = 0; mf < 4; ++mf) acc[d][mf] = (f32x4){0.f, 0.f, 0.f, 0.f};

    // prologue: stage tile 0 into buffer 0
#pragma unroll
    for (int t = 0; t < 8; ++t) { dma16(gsrc[t], ldst[t]); gsrc[t] += 32; }

    int cur = 0;
    for (int it = 0; it < 32; ++it) {
        __syncthreads();
        if (it + 1 < 32) {
#pragma unroll
            for (int t = 0; t < 8; ++t) {
                dma16(gsrc[t], ldst[t] + (cur ^ 1) * 8192);
                gsrc[t] += 32;
            }
        }

        short8 a[4][2], b[4][2];
#pragma unroll
        for (int mf = 0; mf < 4; ++mf)
#pragma unroll
            for (int hl = 0; hl < 2; ++hl)
                a[mf][hl] = *(const short8*)&As[cur][((wm * 4 + mf) * 2 + hl) * 512 + ln * 8];
#pragma unroll
        for (int d = 0; d < 4; ++d)
#pragma unroll
            for (int hl = 0; hl < 2; ++hl)
                b[d][hl] = *(const short8*)&Bs[cur][((d * 2 + wn) * 2 + hl) * 512 + ln * 8];

        // 3 passes x 16 independent MFMAs; per-acc order hh->lh->hl unchanged.
        __builtin_amdgcn_s_setprio(1);
#pragma unroll
        for (int d = 0; d < 4; ++d)
#pragma unroll
            for (int mf = 0; mf < 4; ++mf)
                acc[d][mf] = __builtin_amdgcn_mfma_f32_16x16x32_bf16(a[mf][0], b[d][0], acc[d][mf], 0, 0, 0);
#pragma unroll
        for (int d = 0; d < 4; ++d)
#pragma unroll
            for (int mf = 0; mf < 4; ++mf)
                acc[d][mf] = __builtin_amdgcn_mfma_f32_16x16x32_bf16(a[mf][1], b[d][0], acc[d][mf], 0, 0, 0);
#pragma unroll
        for (int d = 0; d < 4; ++d)
#pragma unroll
            for (int mf = 0; mf < 4; ++mf)
                acc[d][mf] = __builtin_amdgcn_mfma_f32_16x16x32_bf16(a[mf][0], b[d][1], acc[d][mf], 0, 0, 0);
        __builtin_amdgcn_s_setprio(0);
        cur ^= 1;
    }

    const int o = o0 + wn * 16 + (ln & 15);
#pragma unroll
    for (int mf = 0; mf < 4; ++mf)
#pragma unroll
        for (int reg = 0; reg < 4; ++reg) {
            const int b = b0 + wm * 64 + mf * 16 + (ln >> 4) * 4 + reg;
            float tv[4];
#pragma unroll
            for (int d = 0; d < 4; ++d) tv[d] = acc[d][mf][reg];
            float s = rnorm4(tv[0], tv[1], tv[2], tv[3]);
#pragma unroll
            for (int d = 0; d < 4; ++d) {
                float val = tv[d] * s;
                us hi = f2bf(val);
                size_t idx = (size_t)d * PLANE + (size_t)b * OUT_SZ + o;
                Ohi[idx] = hi;
                Olo[idx] = f2bf(val - bf2f(hi));
            }
        }
}

// ------------------------------------------------ launch
extern "C" void kernel_launch(void* const* d_in, const int* in_sizes, int n_in,
                              void* d_out, int out_size, void* d_ws, size_t ws_size,
                              hipStream_t stream) {
    const float* x        = (const float*)d_in[0];
    const float* W_in     = (const float*)d_in[1];
    const float* omega    = (const float*)d_in[2];
    const float* coupling = (const float*)d_in[3];
    float* out = (float*)d_out;

    us* Khi = (us*)d_ws;
    us* Klo = Khi + WPLANE;
    us* Ahi = Klo + WPLANE;          // ping planes (134 MB hi+lo)
    us* Alo = Ahi + 4 * PLANE;
    us* Bhi = (us*)d_out;            // pong planes alias d_out
    us* Blo = Bhi + 4 * PLANE;

    // prep scratch aliased into A region (init consumes before s0 overwrites)
    us* Xhi  = Ahi;
    us* Xlo  = Xhi + (size_t)B_SZ * 1024;
    us* Wthi = Xlo + (size_t)B_SZ * 1024;
    us* Wtlo = Wthi + 4 * WPLANE;

    tanhsplit_kernel<<<(OUT_SZ * OUT_SZ) / 256, 256, 0, stream>>>(coupling, Khi, Klo);
    xsplit_kernel<<<(B_SZ * 1024) / 1024, 256, 0, stream>>>(x, Xhi, Xlo);
    wprep_kernel<<<(4 * OUT_SZ * 64) / 256, 256, 0, stream>>>(W_in, Wthi, Wtlo);

    init_mfma_kernel<<<dim3(B_SZ / 128, OUT_SZ / 32), 256, 0, stream>>>(
        Xhi, Xlo, Wthi, Wtlo, Bhi, Blo);

    for (int s = 0; s < STEPS; ++s) {
        const us* Shi = (s & 1) ? Ahi : Bhi;
        const us* Slo = (s & 1) ? Alo : Blo;
        us*       Dhi = (s & 1) ? Bhi : Ahi;
        us*       Dlo = (s & 1) ? Blo : Alo;
        int fin = (s == STEPS - 1);
        step_mfma_kernel<<<dim3(OUT_SZ / 128, B_SZ / 32), 256, 0, stream>>>(
            Shi, Slo, Khi, Klo, omega, Dhi, Dlo, out, fin);
    }
}

// Round 5
// 2611.564 us; speedup vs baseline: 1.0187x; 1.0187x over previous
//
#include <hip/hip_runtime.h>
#include <math.h>

// AKOrN layer — split-bf16 MFMA for init AND steps, DMA staging, swapped
// operand roles (A = data, B = stationary matrix) so MFMA C-columns are the
// oscillator index -> lane-contiguous epilogue stores.
//
// This revision:
//  * COUNTED-vmcnt pipeline (T4): stage(t) and stage(t+1) both in flight;
//    per-iter `s_waitcnt vmcnt(8)` + raw s_barrier instead of __syncthreads'
//    vmcnt(0) drain. DMA slack grows from ~1 MFMA phase to ~1.5 iterations,
//    covering L3/HBM latency. Double barrier per iter: barrier A (buf ready),
//    barrier B (all reads done -> safe to overwrite with stage t+2).
//  * (kept) 3x16 independent-MFMA passes, setprio around MFMA, XCD swizzle.
//
//   v0 = normalize_d(x @ W_in)            (split-bf16 MFMA)
//   K' = tanh(coupling) + I
//   8x: v = normalize_d(K' v + omega)     (split-bf16 MFMA)

#define B_SZ   8192
#define OUT_SZ 1024
#define STEPS  8
#define PLANE  ((size_t)B_SZ * OUT_SZ)
#define WPLANE ((size_t)OUT_SZ * OUT_SZ)

typedef __attribute__((ext_vector_type(8))) short  short8;
typedef __attribute__((ext_vector_type(4))) float  f32x4;
typedef unsigned short us;

__device__ __forceinline__ us f2bf(float f) {
    union { float f; unsigned u; } v; v.f = f;
    unsigned r = v.u + 0x7FFFu + ((v.u >> 16) & 1u);
    return (us)(r >> 16);
}
__device__ __forceinline__ float bf2f(us h) {
    union { unsigned u; float f; } v; v.u = ((unsigned)h) << 16;
    return v.f;
}
// async global->LDS, 16B per lane, dest = uniform base + lane*16
__device__ __forceinline__ void dma16(const void* g, void* l) {
    __builtin_amdgcn_global_load_lds(
        (const __attribute__((address_space(1))) void*)g,
        (__attribute__((address_space(3))) void*)l, 16, 0, 0);
}
__device__ __forceinline__ float rnorm4(float a, float b, float c, float d) {
    float n2 = a * a + b * b + c * c + d * d;
    float s = rsqrtf(fmaxf(n2, 1e-24f));
    return s * (1.5f - 0.5f * n2 * s * s);   // 1 NR step -> fp32 accuracy
}

// ------------------------------------------------ prep: K' = tanh(c)+I, split
__global__ void tanhsplit_kernel(const float* __restrict__ c,
                                 us* __restrict__ Khi, us* __restrict__ Klo) {
    int idx = blockIdx.x * 256 + threadIdx.x;
    float val = tanhf(c[idx]) + (((idx >> 10) == (idx & (OUT_SZ - 1))) ? 1.0f : 0.0f);
    us hi = f2bf(val);
    Khi[idx] = hi;
    Klo[idx] = f2bf(val - bf2f(hi));
}

// ------------------------------------------------ prep: split x -> bf16 hi/lo
__global__ void xsplit_kernel(const float* __restrict__ x,
                              us* __restrict__ Xhi, us* __restrict__ Xlo) {
    int idx = (blockIdx.x * 256 + threadIdx.x) * 4;
    float4 v = *(const float4*)&x[idx];
    float p[4] = { v.x, v.y, v.z, v.w };
    unsigned h01, h23, l01, l23;
    us h[4], l[4];
#pragma unroll
    for (int t = 0; t < 4; ++t) {
        h[t] = f2bf(p[t]);
        l[t] = f2bf(p[t] - bf2f(h[t]));
    }
    h01 = (unsigned)h[0] | ((unsigned)h[1] << 16);
    h23 = (unsigned)h[2] | ((unsigned)h[3] << 16);
    l01 = (unsigned)l[0] | ((unsigned)l[1] << 16);
    l23 = (unsigned)l[2] | ((unsigned)l[3] << 16);
    ((unsigned*)Xhi)[idx / 2]     = h01;
    ((unsigned*)Xhi)[idx / 2 + 1] = h23;
    ((unsigned*)Xlo)[idx / 2]     = l01;
    ((unsigned*)Xlo)[idx / 2 + 1] = l23;
}

// ------------------------------------------------ prep: W [k][o][d] -> Wt [d][o][k] split
__global__ void wprep_kernel(const float* __restrict__ W,
                             us* __restrict__ Wthi, us* __restrict__ Wtlo) {
    int idx = blockIdx.x * 256 + threadIdx.x;        // 262144 total
    int d  = idx & 3;
    int o  = (idx >> 2) & (OUT_SZ - 1);
    int kc = idx >> 12;                              // 0..63, 16 k each
    us h[16], l[16];
#pragma unroll
    for (int t = 0; t < 16; ++t) {
        float v = W[((size_t)(kc * 16 + t) * OUT_SZ + o) * 4 + d];
        h[t] = f2bf(v);
        l[t] = f2bf(v - bf2f(h[t]));
    }
    size_t base = (size_t)d * WPLANE + (size_t)o * OUT_SZ + kc * 16;
#pragma unroll
    for (int t = 0; t < 16; ++t) { Wthi[base + t] = h[t]; Wtlo[base + t] = l[t]; }
}

// pipeline sync helpers (rule #18: sched_barrier after inline-asm waitcnt)
__device__ __forceinline__ void wait_vm8() {
    asm volatile("s_waitcnt vmcnt(8)" ::: "memory");
    __builtin_amdgcn_sched_barrier(0);
}
__device__ __forceinline__ void wait_vm0() {
    asm volatile("s_waitcnt vmcnt(0)" ::: "memory");
    __builtin_amdgcn_sched_barrier(0);
}
__device__ __forceinline__ void wait_lgkm0() {
    asm volatile("s_waitcnt lgkmcnt(0)" ::: "memory");
    __builtin_amdgcn_sched_barrier(0);
}

// ------------------------------------------------ step: v' = norm(K' v + w)
// A = v (m=b), B = K' (n=i).  Block 32 b x 128 i, 4 waves:
// wm = wv&1 -> 16-b half, wn = wv>>1 -> 64-i half (nf=0..3).
// LDS frag slots: 512 shorts (64 lanes x 16B), lane-linear (DMA-compatible).
// Counted-vmcnt pipeline depth 2: stage(t), stage(t+1) in flight.
__global__ __launch_bounds__(256, 2) void step_mfma_kernel(
    const us* __restrict__ Vhi, const us* __restrict__ Vlo,
    const us* __restrict__ Khi, const us* __restrict__ Klo,
    const float* __restrict__ omega,
    us* __restrict__ Ohi, us* __restrict__ Olo,
    float* __restrict__ out, int final_step)
{
    __shared__ short As[2][8192];   // v tile:  frag (d*2+bh)*2+hl
    __shared__ short Bs[2][8192];   // K' tile: frag ib*2+hl

    const int tid = threadIdx.x;
    const int ln = tid & 63, wv = tid >> 6;
    const int wm = wv & 1, wn = wv >> 1;

    // XCD swizzle: 2048 blocks, lid%8 = XCD. Remap so 8 consecutive work-ids
    // (same b0, all 8 i0 columns) land on ONE XCD -> V tile L2-resident.
    const int lid = blockIdx.y * 8 + blockIdx.x;          // 0..2047
    const int n   = (lid & 7) * 256 + (lid >> 3);         // bijective
    const int i0 = (n & 7) * 128;
    const int b0 = (n >> 3) * 32;

    // 8 DMA frags per wave: waves 0,1 -> A (16 frags), waves 2,3 -> B (16 frags)
    const us* gsrc[8];
    short*    ldst[8];
    if (wv < 2) {
        int t = 0;
#pragma unroll
        for (int dq = 0; dq < 2; ++dq)
#pragma unroll
            for (int bh = 0; bh < 2; ++bh)
#pragma unroll
                for (int hl = 0; hl < 2; ++hl) {
                    int d = wv * 2 + dq;
                    int b = b0 + bh * 16 + (ln & 15);
                    const us* base = hl ? Vlo : Vhi;
                    gsrc[t] = base + (size_t)d * PLANE + (size_t)b * OUT_SZ + (ln >> 4) * 8;
                    ldst[t] = &As[0][((d * 2 + bh) * 2 + hl) * 512];
                    ++t;
                }
    } else {
        int t = 0;
#pragma unroll
        for (int iq = 0; iq < 4; ++iq)
#pragma unroll
            for (int hl = 0; hl < 2; ++hl) {
                int ib = (wv - 2) * 4 + iq;
                int i = i0 + ib * 16 + (ln & 15);
                const us* base = hl ? Klo : Khi;
                gsrc[t] = base + (size_t)i * OUT_SZ + (ln >> 4) * 8;
                ldst[t] = &Bs[0][(ib * 2 + hl) * 512];
                ++t;
            }
    }

    f32x4 acc[4][4];   // [d][nf]
#pragma unroll
    for (int d = 0; d < 4; ++d)
#pragma unroll
        for (int nf = 0; nf < 4; ++nf) acc[d][nf] = (f32x4){0.f, 0.f, 0.f, 0.f};

    // prologue: stage(0) -> buf0, stage(1) -> buf1 (16 outstanding per wave)
#pragma unroll
    for (int t = 0; t < 8; ++t) { dma16(gsrc[t], ldst[t]); gsrc[t] += 32; }
#pragma unroll
    for (int t = 0; t < 8; ++t) { dma16(gsrc[t], ldst[t] + 8192); gsrc[t] += 32; }

    int cur = 0;
    for (int it = 0; it < 32; ++it) {
        if (it < 31) wait_vm8(); else wait_vm0();   // stage(it) landed
        __builtin_amdgcn_s_barrier();               // barrier A: buf[cur] ready

        short8 a[4][2], b[4][2];
#pragma unroll
        for (int d = 0; d < 4; ++d)
#pragma unroll
            for (int hl = 0; hl < 2; ++hl)
                a[d][hl] = *(const short8*)&As[cur][(((d * 2 + wm) * 2 + hl)) * 512 + ln * 8];
#pragma unroll
        for (int nf = 0; nf < 4; ++nf)
#pragma unroll
            for (int hl = 0; hl < 2; ++hl)
                b[nf][hl] = *(const short8*)&Bs[cur][((wn * 4 + nf) * 2 + hl) * 512 + ln * 8];

        wait_lgkm0();                               // my reads complete
        __builtin_amdgcn_s_barrier();               // barrier B: all reads done

        if (it + 2 < 32) {                          // stage(it+2) -> buf[cur]
#pragma unroll
            for (int t = 0; t < 8; ++t) {
                dma16(gsrc[t], ldst[t] + cur * 8192);
                gsrc[t] += 32;
            }
        }

        // 3 passes x 16 independent MFMAs; per-acc order hh->lh->hl unchanged.
        __builtin_amdgcn_s_setprio(1);
#pragma unroll
        for (int d = 0; d < 4; ++d)
#pragma unroll
            for (int nf = 0; nf < 4; ++nf)
                acc[d][nf] = __builtin_amdgcn_mfma_f32_16x16x32_bf16(a[d][0], b[nf][0], acc[d][nf], 0, 0, 0);
#pragma unroll
        for (int d = 0; d < 4; ++d)
#pragma unroll
            for (int nf = 0; nf < 4; ++nf)
                acc[d][nf] = __builtin_amdgcn_mfma_f32_16x16x32_bf16(a[d][1], b[nf][0], acc[d][nf], 0, 0, 0);
#pragma unroll
        for (int d = 0; d < 4; ++d)
#pragma unroll
            for (int nf = 0; nf < 4; ++nf)
                acc[d][nf] = __builtin_amdgcn_mfma_f32_16x16x32_bf16(a[d][0], b[nf][1], acc[d][nf], 0, 0, 0);
        __builtin_amdgcn_s_setprio(0);
        cur ^= 1;
    }

    // epilogue: C row = b, col = i (lane-contiguous stores)
#pragma unroll
    for (int nf = 0; nf < 4; ++nf) {
        const int i = i0 + wn * 64 + nf * 16 + (ln & 15);
        const f32x4 om = *(const f32x4*)&omega[i * 4];
#pragma unroll
        for (int reg = 0; reg < 4; ++reg) {
            const int b = b0 + wm * 16 + (ln >> 4) * 4 + reg;
            float tv[4];
#pragma unroll
            for (int d = 0; d < 4; ++d) tv[d] = acc[d][nf][reg] + om[d];
            float s = rnorm4(tv[0], tv[1], tv[2], tv[3]);
            if (final_step) {
                f32x4 rr = { tv[0] * s, tv[1] * s, tv[2] * s, tv[3] * s };
                *(f32x4*)&out[((size_t)b * OUT_SZ + i) * 4] = rr;
            } else {
#pragma unroll
                for (int d = 0; d < 4; ++d) {
                    float val = tv[d] * s;
                    us hi = f2bf(val);
                    size_t idx = (size_t)d * PLANE + (size_t)b * OUT_SZ + i;
                    Ohi[idx] = hi;
                    Olo[idx] = f2bf(val - bf2f(hi));
                }
            }
        }
    }
}

// ------------------------------------------------ init: v0 = norm(x @ W)
// A = x (m=b, d-independent), B = Wt planes (n=o, per d).
// Block 128 b x 32 o, 4 waves: wm -> 64-b half (mf=0..3), wn -> 16-o half.
// Same counted-vmcnt pipeline as the step kernel.
__global__ __launch_bounds__(256, 2) void init_mfma_kernel(
    const us* __restrict__ Xhi, const us* __restrict__ Xlo,
    const us* __restrict__ Wthi, const us* __restrict__ Wtlo,
    us* __restrict__ Ohi, us* __restrict__ Olo)
{
    __shared__ short As[2][8192];   // x tile:  frag bf*2+hl  (bf=0..7)
    __shared__ short Bs[2][8192];   // Wt tile: frag (d*2+oh)*2+hl

    const int tid = threadIdx.x;
    const int ln = tid & 63, wv = tid >> 6;
    const int wm = wv & 1, wn = wv >> 1;

    // swizzle: 8 consecutive work-ids (same o-tile group) per XCD -> Wt L2-reuse
    const int lid = blockIdx.y * 64 + blockIdx.x;         // 0..2047
    const int n   = (lid & 7) * 256 + (lid >> 3);         // bijective
    const int b0 = (n & 63) * 128;
    const int o0 = (n >> 6) * 32;

    const us* gsrc[8];
    short*    ldst[8];
    if (wv < 2) {
        int t = 0;
#pragma unroll
        for (int bq = 0; bq < 4; ++bq)
#pragma unroll
            for (int hl = 0; hl < 2; ++hl) {
                int bf = wv * 4 + bq;
                int b = b0 + bf * 16 + (ln & 15);
                const us* base = hl ? Xlo : Xhi;
                gsrc[t] = base + (size_t)b * 1024 + (ln >> 4) * 8;
                ldst[t] = &As[0][(bf * 2 + hl) * 512];
                ++t;
            }
    } else {
        int t = 0;
#pragma unroll
        for (int dq = 0; dq < 2; ++dq)
#pragma unroll
            for (int oh = 0; oh < 2; ++oh)
#pragma unroll
                for (int hl = 0; hl < 2; ++hl) {
                    int d = (wv - 2) * 2 + dq;
                    int o = o0 + oh * 16 + (ln & 15);
                    const us* base = hl ? Wtlo : Wthi;
                    gsrc[t] = base + (size_t)d * WPLANE + (size_t)o * OUT_SZ + (ln >> 4) * 8;
                    ldst[t] = &Bs[0][((d * 2 + oh) * 2 + hl) * 512];
                    ++t;
                }
    }

    f32x4 acc[4][4];   // [d][mf]
#pragma unroll
    for (int d = 0; d < 4; ++d)
#pragma unroll
        for (int mf = 0; mf < 4; ++mf) acc[d][mf] = (f32x4){0.f, 0.f, 0.f, 0.f};

    // prologue: stage(0) -> buf0, stage(1) -> buf1
#pragma unroll
    for (int t = 0; t < 8; ++t) { dma16(gsrc[t], ldst[t]); gsrc[t] += 32; }
#pragma unroll
    for (int t = 0; t < 8; ++t) { dma16(gsrc[t], ldst[t] + 8192); gsrc[t] += 32; }

    int cur = 0;
    for (int it = 0; it < 32; ++it) {
        if (it < 31) wait_vm8(); else wait_vm0();
        __builtin_amdgcn_s_barrier();               // barrier A: buf[cur] ready

        short8 a[4][2], b[4][2];
#pragma unroll
        for (int mf = 0; mf < 4; ++mf)
#pragma unroll
            for (int hl = 0; hl < 2; ++hl)
                a[mf][hl] = *(const short8*)&As[cur][((wm * 4 + mf) * 2 + hl) * 512 + ln * 8];
#pragma unroll
        for (int d = 0; d < 4; ++d)
#pragma unroll
            for (int hl = 0; hl < 2; ++hl)
                b[d][hl] = *(const short8*)&Bs[cur][((d * 2 + wn) * 2 + hl) * 512 + ln * 8];

        wait_lgkm0();
        __builtin_amdgcn_s_barrier();               // barrier B: all reads done

        if (it + 2 < 32) {
#pragma unroll
            for (int t = 0; t < 8; ++t) {
                dma16(gsrc[t], ldst[t] + cur * 8192);
                gsrc[t] += 32;
            }
        }

        // 3 passes x 16 independent MFMAs; per-acc order hh->lh->hl unchanged.
        __builtin_amdgcn_s_setprio(1);
#pragma unroll
        for (int d = 0; d < 4; ++d)
#pragma unroll
            for (int mf = 0; mf < 4; ++mf)
                acc[d][mf] = __builtin_amdgcn_mfma_f32_16x16x32_bf16(a[mf][0], b[d][0], acc[d][mf], 0, 0, 0);
#pragma unroll
        for (int d = 0; d < 4; ++d)
#pragma unroll
            for (int mf = 0; mf < 4; ++mf)
                acc[d][mf] = __builtin_amdgcn_mfma_f32_16x16x32_bf16(a[mf][1], b[d][0], acc[d][mf], 0, 0, 0);
#pragma unroll
        for (int d = 0; d < 4; ++d)
#pragma unroll
            for (int mf = 0; mf < 4; ++mf)
                acc[d][mf] = __builtin_amdgcn_mfma_f32_16x16x32_bf16(a[mf][0], b[d][1], acc[d][mf], 0, 0, 0);
        __builtin_amdgcn_s_setprio(0);
        cur ^= 1;
    }

    const int o = o0 + wn * 16 + (ln & 15);
#pragma unroll
    for (int mf = 0; mf < 4; ++mf)
#pragma unroll
        for (int reg = 0; reg < 4; ++reg) {
            const int b = b0 + wm * 64 + mf * 16 + (ln >> 4) * 4 + reg;
            float tv[4];
#pragma unroll
            for (int d = 0; d < 4; ++d) tv[d] = acc[d][mf][reg];
            float s = rnorm4(tv[0], tv[1], tv[2], tv[3]);
#pragma unroll
            for (int d = 0; d < 4; ++d) {
                float val = tv[d] * s;
                us hi = f2bf(val);
                size_t idx = (size_t)d * PLANE + (size_t)b * OUT_SZ + o;
                Ohi[idx] = hi;
                Olo[idx] = f2bf(val - bf2f(hi));
            }
        }
}

// ------------------------------------------------ launch
extern "C" void kernel_launch(void* const* d_in, const int* in_sizes, int n_in,
                              void* d_out, int out_size, void* d_ws, size_t ws_size,
                              hipStream_t stream) {
    const float* x        = (const float*)d_in[0];
    const float* W_in     = (const float*)d_in[1];
    const float* omega    = (const float*)d_in[2];
    const float* coupling = (const float*)d_in[3];
    float* out = (float*)d_out;

    us* Khi = (us*)d_ws;
    us* Klo = Khi + WPLANE;
    us* Ahi = Klo + WPLANE;          // ping planes (134 MB hi+lo)
    us* Alo = Ahi + 4 * PLANE;
    us* Bhi = (us*)d_out;            // pong planes alias d_out
    us* Blo = Bhi + 4 * PLANE;

    // prep scratch aliased into A region (init consumes before s0 overwrites)
    us* Xhi  = Ahi;
    us* Xlo  = Xhi + (size_t)B_SZ * 1024;
    us* Wthi = Xlo + (size_t)B_SZ * 1024;
    us* Wtlo = Wthi + 4 * WPLANE;

    tanhsplit_kernel<<<(OUT_SZ * OUT_SZ) / 256, 256, 0, stream>>>(coupling, Khi, Klo);
    xsplit_kernel<<<(B_SZ * 1024) / 1024, 256, 0, stream>>>(x, Xhi, Xlo);
    wprep_kernel<<<(4 * OUT_SZ * 64) / 256, 256, 0, stream>>>(W_in, Wthi, Wtlo);

    init_mfma_kernel<<<dim3(B_SZ / 128, OUT_SZ / 32), 256, 0, stream>>>(
        Xhi, Xlo, Wthi, Wtlo, Bhi, Blo);

    for (int s = 0; s < STEPS; ++s) {
        const us* Shi = (s & 1) ? Ahi : Bhi;
        const us* Slo = (s & 1) ? Alo : Blo;
        us*       Dhi = (s & 1) ? Bhi : Ahi;
        us*       Dlo = (s & 1) ? Blo : Alo;
        int fin = (s == STEPS - 1);
        step_mfma_kernel<<<dim3(OUT_SZ / 128, B_SZ / 32), 256, 0, stream>>>(
            Shi, Slo, Khi, Klo, omega, Dhi, Dlo, out, fin);
    }
}

// Round 6
// 2601.747 us; speedup vs baseline: 1.0225x; 1.0038x over previous
//
#include <hip/hip_runtime.h>
#include <math.h>

// AKOrN layer — split-bf16 MFMA for init AND steps, DMA staging, swapped
// operand roles (A = data, B = stationary matrix) so MFMA C-columns are the
// oscillator index -> lane-contiguous epilogue stores.
//
// This revision (occupancy):
//  * LDS 64 KB -> 48 KB: B tile (K'/Wt, L2-resident via XCD swizzle) is
//    SINGLE-buffered; its stage(t+1) is issued after barrier B of iter t and
//    waited with vmcnt(0) at top of t+1 — one MFMA phase (~930cy) covers L2
//    latency (~250cy). A tile (V/x, HBM-latency) keeps depth-2 counted vmcnt.
//    48 KB/block -> 3 blocks/CU (waves/SIMD 2 -> 3), launch_bounds(256,3).
//  * (kept) counted-vmcnt pipeline, 3x16 independent-MFMA passes, setprio,
//    XCD-aware block swizzle.
//
//   v0 = normalize_d(x @ W_in)            (split-bf16 MFMA)
//   K' = tanh(coupling) + I
//   8x: v = normalize_d(K' v + omega)     (split-bf16 MFMA)

#define B_SZ   8192
#define OUT_SZ 1024
#define STEPS  8
#define PLANE  ((size_t)B_SZ * OUT_SZ)
#define WPLANE ((size_t)OUT_SZ * OUT_SZ)

typedef __attribute__((ext_vector_type(8))) short  short8;
typedef __attribute__((ext_vector_type(4))) float  f32x4;
typedef unsigned short us;

__device__ __forceinline__ us f2bf(float f) {
    union { float f; unsigned u; } v; v.f = f;
    unsigned r = v.u + 0x7FFFu + ((v.u >> 16) & 1u);
    return (us)(r >> 16);
}
__device__ __forceinline__ float bf2f(us h) {
    union { unsigned u; float f; } v; v.u = ((unsigned)h) << 16;
    return v.f;
}
// async global->LDS, 16B per lane, dest = uniform base + lane*16
__device__ __forceinline__ void dma16(const void* g, void* l) {
    __builtin_amdgcn_global_load_lds(
        (const __attribute__((address_space(1))) void*)g,
        (__attribute__((address_space(3))) void*)l, 16, 0, 0);
}
__device__ __forceinline__ float rnorm4(float a, float b, float c, float d) {
    float n2 = a * a + b * b + c * c + d * d;
    float s = rsqrtf(fmaxf(n2, 1e-24f));
    return s * (1.5f - 0.5f * n2 * s * s);   // 1 NR step -> fp32 accuracy
}

// ------------------------------------------------ prep: K' = tanh(c)+I, split
__global__ void tanhsplit_kernel(const float* __restrict__ c,
                                 us* __restrict__ Khi, us* __restrict__ Klo) {
    int idx = blockIdx.x * 256 + threadIdx.x;
    float val = tanhf(c[idx]) + (((idx >> 10) == (idx & (OUT_SZ - 1))) ? 1.0f : 0.0f);
    us hi = f2bf(val);
    Khi[idx] = hi;
    Klo[idx] = f2bf(val - bf2f(hi));
}

// ------------------------------------------------ prep: split x -> bf16 hi/lo
__global__ void xsplit_kernel(const float* __restrict__ x,
                              us* __restrict__ Xhi, us* __restrict__ Xlo) {
    int idx = (blockIdx.x * 256 + threadIdx.x) * 4;
    float4 v = *(const float4*)&x[idx];
    float p[4] = { v.x, v.y, v.z, v.w };
    unsigned h01, h23, l01, l23;
    us h[4], l[4];
#pragma unroll
    for (int t = 0; t < 4; ++t) {
        h[t] = f2bf(p[t]);
        l[t] = f2bf(p[t] - bf2f(h[t]));
    }
    h01 = (unsigned)h[0] | ((unsigned)h[1] << 16);
    h23 = (unsigned)h[2] | ((unsigned)h[3] << 16);
    l01 = (unsigned)l[0] | ((unsigned)l[1] << 16);
    l23 = (unsigned)l[2] | ((unsigned)l[3] << 16);
    ((unsigned*)Xhi)[idx / 2]     = h01;
    ((unsigned*)Xhi)[idx / 2 + 1] = h23;
    ((unsigned*)Xlo)[idx / 2]     = l01;
    ((unsigned*)Xlo)[idx / 2 + 1] = l23;
}

// ------------------------------------------------ prep: W [k][o][d] -> Wt [d][o][k] split
__global__ void wprep_kernel(const float* __restrict__ W,
                             us* __restrict__ Wthi, us* __restrict__ Wtlo) {
    int idx = blockIdx.x * 256 + threadIdx.x;        // 262144 total
    int d  = idx & 3;
    int o  = (idx >> 2) & (OUT_SZ - 1);
    int kc = idx >> 12;                              // 0..63, 16 k each
    us h[16], l[16];
#pragma unroll
    for (int t = 0; t < 16; ++t) {
        float v = W[((size_t)(kc * 16 + t) * OUT_SZ + o) * 4 + d];
        h[t] = f2bf(v);
        l[t] = f2bf(v - bf2f(h[t]));
    }
    size_t base = (size_t)d * WPLANE + (size_t)o * OUT_SZ + kc * 16;
#pragma unroll
    for (int t = 0; t < 16; ++t) { Wthi[base + t] = h[t]; Wtlo[base + t] = l[t]; }
}

// pipeline sync helpers (rule #18: sched_barrier after inline-asm waitcnt)
__device__ __forceinline__ void wait_vm8() {
    asm volatile("s_waitcnt vmcnt(8)" ::: "memory");
    __builtin_amdgcn_sched_barrier(0);
}
__device__ __forceinline__ void wait_vm0() {
    asm volatile("s_waitcnt vmcnt(0)" ::: "memory");
    __builtin_amdgcn_sched_barrier(0);
}
__device__ __forceinline__ void wait_lgkm0() {
    asm volatile("s_waitcnt lgkmcnt(0)" ::: "memory");
    __builtin_amdgcn_sched_barrier(0);
}

// ------------------------------------------------ step: v' = norm(K' v + w)
// A = v (m=b), B = K' (n=i).  Block 32 b x 128 i, 4 waves:
// wm = wv&1 -> 16-b half, wn = wv>>1 -> 64-i half (nf=0..3).
// LDS frag slots: 512 shorts (64 lanes x 16B), lane-linear (DMA-compatible).
// A: double-buffered depth-2 counted vmcnt (waves 0,1).
// B: single-buffered, staged by waves 2,3 one iter ahead (L2-resident).
__global__ __launch_bounds__(256, 3) void step_mfma_kernel(
    const us* __restrict__ Vhi, const us* __restrict__ Vlo,
    const us* __restrict__ Khi, const us* __restrict__ Klo,
    const float* __restrict__ omega,
    us* __restrict__ Ohi, us* __restrict__ Olo,
    float* __restrict__ out, int final_step)
{
    __shared__ short As[2][8192];   // v tile:  frag (d*2+bh)*2+hl (dbuf)
    __shared__ short Bs[8192];      // K' tile: frag ib*2+hl (single)

    const int tid = threadIdx.x;
    const int ln = tid & 63, wv = tid >> 6;
    const int wm = wv & 1, wn = wv >> 1;

    // XCD swizzle: 2048 blocks, lid%8 = XCD. Remap so 8 consecutive work-ids
    // (same b0, all 8 i0 columns) land on ONE XCD -> V tile L2-resident.
    const int lid = blockIdx.y * 8 + blockIdx.x;          // 0..2047
    const int n   = (lid & 7) * 256 + (lid >> 3);         // bijective
    const int i0 = (n & 7) * 128;
    const int b0 = (n >> 3) * 32;

    // 8 DMA frags per wave: waves 0,1 -> A (16 frags), waves 2,3 -> B (16 frags)
    const us* gsrc[8];
    short*    ldst[8];
    if (wv < 2) {
        int t = 0;
#pragma unroll
        for (int dq = 0; dq < 2; ++dq)
#pragma unroll
            for (int bh = 0; bh < 2; ++bh)
#pragma unroll
                for (int hl = 0; hl < 2; ++hl) {
                    int d = wv * 2 + dq;
                    int b = b0 + bh * 16 + (ln & 15);
                    const us* base = hl ? Vlo : Vhi;
                    gsrc[t] = base + (size_t)d * PLANE + (size_t)b * OUT_SZ + (ln >> 4) * 8;
                    ldst[t] = &As[0][((d * 2 + bh) * 2 + hl) * 512];
                    ++t;
                }
    } else {
        int t = 0;
#pragma unroll
        for (int iq = 0; iq < 4; ++iq)
#pragma unroll
            for (int hl = 0; hl < 2; ++hl) {
                int ib = (wv - 2) * 4 + iq;
                int i = i0 + ib * 16 + (ln & 15);
                const us* base = hl ? Klo : Khi;
                gsrc[t] = base + (size_t)i * OUT_SZ + (ln >> 4) * 8;
                ldst[t] = &Bs[(ib * 2 + hl) * 512];
                ++t;
            }
    }

    f32x4 acc[4][4];   // [d][nf]
#pragma unroll
    for (int d = 0; d < 4; ++d)
#pragma unroll
        for (int nf = 0; nf < 4; ++nf) acc[d][nf] = (f32x4){0.f, 0.f, 0.f, 0.f};

    // prologue: A waves stage A(0)->buf0, A(1)->buf1; B waves stage B(0).
    if (wv < 2) {
#pragma unroll
        for (int t = 0; t < 8; ++t) { dma16(gsrc[t], ldst[t]); gsrc[t] += 32; }
#pragma unroll
        for (int t = 0; t < 8; ++t) { dma16(gsrc[t], ldst[t] + 8192); gsrc[t] += 32; }
    } else {
#pragma unroll
        for (int t = 0; t < 8; ++t) { dma16(gsrc[t], ldst[t]); gsrc[t] += 32; }
    }

    int cur = 0;
    for (int it = 0; it < 32; ++it) {
        // A waves: stage(it) landed, stage(it+1) may fly. B waves: all landed.
        if (wv < 2) { if (it < 31) wait_vm8(); else wait_vm0(); }
        else        { wait_vm0(); }
        __builtin_amdgcn_s_barrier();               // barrier A: tiles ready

        short8 a[4][2], b[4][2];
#pragma unroll
        for (int d = 0; d < 4; ++d)
#pragma unroll
            for (int hl = 0; hl < 2; ++hl)
                a[d][hl] = *(const short8*)&As[cur][(((d * 2 + wm) * 2 + hl)) * 512 + ln * 8];
#pragma unroll
        for (int nf = 0; nf < 4; ++nf)
#pragma unroll
            for (int hl = 0; hl < 2; ++hl)
                b[nf][hl] = *(const short8*)&Bs[((wn * 4 + nf) * 2 + hl) * 512 + ln * 8];

        wait_lgkm0();                               // my reads complete
        __builtin_amdgcn_s_barrier();               // barrier B: all reads done

        if (wv < 2) {
            if (it + 2 < 32) {                      // stage A(it+2) -> As[cur]
#pragma unroll
                for (int t = 0; t < 8; ++t) {
                    dma16(gsrc[t], ldst[t] + cur * 8192);
                    gsrc[t] += 32;
                }
            }
        } else {
            if (it + 1 < 32) {                      // stage B(it+1) -> Bs
#pragma unroll
                for (int t = 0; t < 8; ++t) {
                    dma16(gsrc[t], ldst[t]);
                    gsrc[t] += 32;
                }
            }
        }

        // 3 passes x 16 independent MFMAs; per-acc order hh->lh->hl unchanged.
        __builtin_amdgcn_s_setprio(1);
#pragma unroll
        for (int d = 0; d < 4; ++d)
#pragma unroll
            for (int nf = 0; nf < 4; ++nf)
                acc[d][nf] = __builtin_amdgcn_mfma_f32_16x16x32_bf16(a[d][0], b[nf][0], acc[d][nf], 0, 0, 0);
#pragma unroll
        for (int d = 0; d < 4; ++d)
#pragma unroll
            for (int nf = 0; nf < 4; ++nf)
                acc[d][nf] = __builtin_amdgcn_mfma_f32_16x16x32_bf16(a[d][1], b[nf][0], acc[d][nf], 0, 0, 0);
#pragma unroll
        for (int d = 0; d < 4; ++d)
#pragma unroll
            for (int nf = 0; nf < 4; ++nf)
                acc[d][nf] = __builtin_amdgcn_mfma_f32_16x16x32_bf16(a[d][0], b[nf][1], acc[d][nf], 0, 0, 0);
        __builtin_amdgcn_s_setprio(0);
        cur ^= 1;
    }

    // epilogue: C row = b, col = i (lane-contiguous stores)
#pragma unroll
    for (int nf = 0; nf < 4; ++nf) {
        const int i = i0 + wn * 64 + nf * 16 + (ln & 15);
        const f32x4 om = *(const f32x4*)&omega[i * 4];
#pragma unroll
        for (int reg = 0; reg < 4; ++reg) {
            const int b = b0 + wm * 16 + (ln >> 4) * 4 + reg;
            float tv[4];
#pragma unroll
            for (int d = 0; d < 4; ++d) tv[d] = acc[d][nf][reg] + om[d];
            float s = rnorm4(tv[0], tv[1], tv[2], tv[3]);
            if (final_step) {
                f32x4 rr = { tv[0] * s, tv[1] * s, tv[2] * s, tv[3] * s };
                *(f32x4*)&out[((size_t)b * OUT_SZ + i) * 4] = rr;
            } else {
#pragma unroll
                for (int d = 0; d < 4; ++d) {
                    float val = tv[d] * s;
                    us hi = f2bf(val);
                    size_t idx = (size_t)d * PLANE + (size_t)b * OUT_SZ + i;
                    Ohi[idx] = hi;
                    Olo[idx] = f2bf(val - bf2f(hi));
                }
            }
        }
    }
}

// ------------------------------------------------ init: v0 = norm(x @ W)
// A = x (m=b, d-independent), B = Wt planes (n=o, per d).
// Block 128 b x 32 o, 4 waves: wm -> 64-b half (mf=0..3), wn -> 16-o half.
// Same A-dbuf / B-single structure as the step kernel.
__global__ __launch_bounds__(256, 3) void init_mfma_kernel(
    const us* __restrict__ Xhi, const us* __restrict__ Xlo,
    const us* __restrict__ Wthi, const us* __restrict__ Wtlo,
    us* __restrict__ Ohi, us* __restrict__ Olo)
{
    __shared__ short As[2][8192];   // x tile:  frag bf*2+hl  (bf=0..7, dbuf)
    __shared__ short Bs[8192];      // Wt tile: frag (d*2+oh)*2+hl (single)

    const int tid = threadIdx.x;
    const int ln = tid & 63, wv = tid >> 6;
    const int wm = wv & 1, wn = wv >> 1;

    // swizzle: 8 consecutive work-ids (same o-tile group) per XCD -> Wt L2-reuse
    const int lid = blockIdx.y * 64 + blockIdx.x;         // 0..2047
    const int n   = (lid & 7) * 256 + (lid >> 3);         // bijective
    const int b0 = (n & 63) * 128;
    const int o0 = (n >> 6) * 32;

    const us* gsrc[8];
    short*    ldst[8];
    if (wv < 2) {
        int t = 0;
#pragma unroll
        for (int bq = 0; bq < 4; ++bq)
#pragma unroll
            for (int hl = 0; hl < 2; ++hl) {
                int bf = wv * 4 + bq;
                int b = b0 + bf * 16 + (ln & 15);
                const us* base = hl ? Xlo : Xhi;
                gsrc[t] = base + (size_t)b * 1024 + (ln >> 4) * 8;
                ldst[t] = &As[0][(bf * 2 + hl) * 512];
                ++t;
            }
    } else {
        int t = 0;
#pragma unroll
        for (int dq = 0; dq < 2; ++dq)
#pragma unroll
            for (int oh = 0; oh < 2; ++oh)
#pragma unroll
                for (int hl = 0; hl < 2; ++hl) {
                    int d = (wv - 2) * 2 + dq;
                    int o = o0 + oh * 16 + (ln & 15);
                    const us* base = hl ? Wtlo : Wthi;
                    gsrc[t] = base + (size_t)d * WPLANE + (size_t)o * OUT_SZ + (ln >> 4) * 8;
                    ldst[t] = &Bs[((d * 2 + oh) * 2 + hl) * 512];
                    ++t;
                }
    }

    f32x4 acc[4][4];   // [d][mf]
#pragma unroll
    for (int d = 0; d < 4; ++d)
#pragma unroll
        for (int mf = 0; mf < 4; ++mf) acc[d][mf] = (f32x4){0.f, 0.f, 0.f, 0.f};

    // prologue
    if (wv < 2) {
#pragma unroll
        for (int t = 0; t < 8; ++t) { dma16(gsrc[t], ldst[t]); gsrc[t] += 32; }
#pragma unroll
        for (int t = 0; t < 8; ++t) { dma16(gsrc[t], ldst[t] + 8192); gsrc[t] += 32; }
    } else {
#pragma unroll
        for (int t = 0; t < 8; ++t) { dma16(gsrc[t], ldst[t]); gsrc[t] += 32; }
    }

    int cur = 0;
    for (int it = 0; it < 32; ++it) {
        if (wv < 2) { if (it < 31) wait_vm8(); else wait_vm0(); }
        else        { wait_vm0(); }
        __builtin_amdgcn_s_barrier();               // barrier A: tiles ready

        short8 a[4][2], b[4][2];
#pragma unroll
        for (int mf = 0; mf < 4; ++mf)
#pragma unroll
            for (int hl = 0; hl < 2; ++hl)
                a[mf][hl] = *(const short8*)&As[cur][((wm * 4 + mf) * 2 + hl) * 512 + ln * 8];
#pragma unroll
        for (int d = 0; d < 4; ++d)
#pragma unroll
            for (int hl = 0; hl < 2; ++hl)
                b[d][hl] = *(const short8*)&Bs[((d * 2 + wn) * 2 + hl) * 512 + ln * 8];

        wait_lgkm0();
        __builtin_amdgcn_s_barrier();               // barrier B: all reads done

        if (wv < 2) {
            if (it + 2 < 32) {
#pragma unroll
                for (int t = 0; t < 8; ++t) {
                    dma16(gsrc[t], ldst[t] + cur * 8192);
                    gsrc[t] += 32;
                }
            }
        } else {
            if (it + 1 < 32) {
#pragma unroll
                for (int t = 0; t < 8; ++t) {
                    dma16(gsrc[t], ldst[t]);
                    gsrc[t] += 32;
                }
            }
        }

        // 3 passes x 16 independent MFMAs; per-acc order hh->lh->hl unchanged.
        __builtin_amdgcn_s_setprio(1);
#pragma unroll
        for (int d = 0; d < 4; ++d)
#pragma unroll
            for (int mf = 0; mf < 4; ++mf)
                acc[d][mf] = __builtin_amdgcn_mfma_f32_16x16x32_bf16(a[mf][0], b[d][0], acc[d][mf], 0, 0, 0);
#pragma unroll
        for (int d = 0; d < 4; ++d)
#pragma unroll
            for (int mf = 0; mf < 4; ++mf)
                acc[d][mf] = __builtin_amdgcn_mfma_f32_16x16x32_bf16(a[mf][1], b[d][0], acc[d][mf], 0, 0, 0);
#pragma unroll
        for (int d = 0; d < 4; ++d)
#pragma unroll
            for (int mf = 0; mf < 4; ++mf)
                acc[d][mf] = __builtin_amdgcn_mfma_f32_16x16x32_bf16(a[mf][0], b[d][1], acc[d][mf], 0, 0, 0);
        __builtin_amdgcn_s_setprio(0);
        cur ^= 1;
    }

    const int o = o0 + wn * 16 + (ln & 15);
#pragma unroll
    for (int mf = 0; mf < 4; ++mf)
#pragma unroll
        for (int reg = 0; reg < 4; ++reg) {
            const int b = b0 + wm * 64 + mf * 16 + (ln >> 4) * 4 + reg;
            float tv[4];
#pragma unroll
            for (int d = 0; d < 4; ++d) tv[d] = acc[d][mf][reg];
            float s = rnorm4(tv[0], tv[1], tv[2], tv[3]);
#pragma unroll
            for (int d = 0; d < 4; ++d) {
                float val = tv[d] * s;
                us hi = f2bf(val);
                size_t idx = (size_t)d * PLANE + (size_t)b * OUT_SZ + o;
                Ohi[idx] = hi;
                Olo[idx] = f2bf(val - bf2f(hi));
            }
        }
}

// ------------------------------------------------ launch
extern "C" void kernel_launch(void* const* d_in, const int* in_sizes, int n_in,
                              void* d_out, int out_size, void* d_ws, size_t ws_size,
                              hipStream_t stream) {
    const float* x        = (const float*)d_in[0];
    const float* W_in     = (const float*)d_in[1];
    const float* omega    = (const float*)d_in[2];
    const float* coupling = (const float*)d_in[3];
    float* out = (float*)d_out;

    us* Khi = (us*)d_ws;
    us* Klo = Khi + WPLANE;
    us* Ahi = Klo + WPLANE;          // ping planes (134 MB hi+lo)
    us* Alo = Ahi + 4 * PLANE;
    us* Bhi = (us*)d_out;            // pong planes alias d_out
    us* Blo = Bhi + 4 * PLANE;

    // prep scratch aliased into A region (init consumes before s0 overwrites)
    us* Xhi  = Ahi;
    us* Xlo  = Xhi + (size_t)B_SZ * 1024;
    us* Wthi = Xlo + (size_t)B_SZ * 1024;
    us* Wtlo = Wthi + 4 * WPLANE;

    tanhsplit_kernel<<<(OUT_SZ * OUT_SZ) / 256, 256, 0, stream>>>(coupling, Khi, Klo);
    xsplit_kernel<<<(B_SZ * 1024) / 1024, 256, 0, stream>>>(x, Xhi, Xlo);
    wprep_kernel<<<(4 * OUT_SZ * 64) / 256, 256, 0, stream>>>(W_in, Wthi, Wtlo);

    init_mfma_kernel<<<dim3(B_SZ / 128, OUT_SZ / 32), 256, 0, stream>>>(
        Xhi, Xlo, Wthi, Wtlo, Bhi, Blo);

    for (int s = 0; s < STEPS; ++s) {
        const us* Shi = (s & 1) ? Ahi : Bhi;
        const us* Slo = (s & 1) ? Alo : Blo;
        us*       Dhi = (s & 1) ? Bhi : Ahi;
        us*       Dlo = (s & 1) ? Blo : Alo;
        int fin = (s == STEPS - 1);
        step_mfma_kernel<<<dim3(OUT_SZ / 128, B_SZ / 32), 256, 0, stream>>>(
            Shi, Slo, Khi, Klo, omega, Dhi, Dlo, out, fin);
    }
}

// Round 7
// 2265.348 us; speedup vs baseline: 1.1744x; 1.1485x over previous
//
#include <hip/hip_runtime.h>
#include <math.h>

// AKOrN layer — split-bf16 MFMA, DMA staging, swapped operand roles.
//
// This revision (staged-bytes cut, 2x):
//  * Diagnosis: kernel is VMEM->LDS THROUGHPUT-bound: 2.1 GB staged/step at
//    the 6.3 TB/s global-load ceiling == measured 327 us. MfmaUtil 30% is
//    exactly the 99us MFMA floor / wall. Fix = bigger tiles (fewer staged
//    bytes per output), not more pipelining.
//  * Step: block 64b x 256i, 8 waves (512 thr), staged 1.07 GB/step (was 2.1).
//  * Init: block 256b x 64o, 8 waves, staged 1.07 GB (was 2.1).
//  * Both: A,B double-buffered (128 KB LDS, 1 block/CU), depth-2 counted
//    vmcnt(8) pipeline, two raw barriers/iter (round-5/6 proven skeleton),
//    3-pass independent MFMAs, setprio, XCD-grouped swizzle.
//  * Accumulation order per-acc unchanged -> bit-identical numerics.

#define B_SZ   8192
#define OUT_SZ 1024
#define STEPS  8
#define PLANE  ((size_t)B_SZ * OUT_SZ)
#define WPLANE ((size_t)OUT_SZ * OUT_SZ)

typedef __attribute__((ext_vector_type(8))) short  short8;
typedef __attribute__((ext_vector_type(4))) float  f32x4;
typedef unsigned short us;

__device__ __forceinline__ us f2bf(float f) {
    union { float f; unsigned u; } v; v.f = f;
    unsigned r = v.u + 0x7FFFu + ((v.u >> 16) & 1u);
    return (us)(r >> 16);
}
__device__ __forceinline__ float bf2f(us h) {
    union { unsigned u; float f; } v; v.u = ((unsigned)h) << 16;
    return v.f;
}
// async global->LDS, 16B per lane, dest = uniform base + lane*16
__device__ __forceinline__ void dma16(const void* g, void* l) {
    __builtin_amdgcn_global_load_lds(
        (const __attribute__((address_space(1))) void*)g,
        (__attribute__((address_space(3))) void*)l, 16, 0, 0);
}
__device__ __forceinline__ float rnorm4(float a, float b, float c, float d) {
    float n2 = a * a + b * b + c * c + d * d;
    float s = rsqrtf(fmaxf(n2, 1e-24f));
    return s * (1.5f - 0.5f * n2 * s * s);   // 1 NR step -> fp32 accuracy
}

// ------------------------------------------------ prep: K' = tanh(c)+I, split
__global__ void tanhsplit_kernel(const float* __restrict__ c,
                                 us* __restrict__ Khi, us* __restrict__ Klo) {
    int idx = blockIdx.x * 256 + threadIdx.x;
    float val = tanhf(c[idx]) + (((idx >> 10) == (idx & (OUT_SZ - 1))) ? 1.0f : 0.0f);
    us hi = f2bf(val);
    Khi[idx] = hi;
    Klo[idx] = f2bf(val - bf2f(hi));
}

// ------------------------------------------------ prep: split x -> bf16 hi/lo
__global__ void xsplit_kernel(const float* __restrict__ x,
                              us* __restrict__ Xhi, us* __restrict__ Xlo) {
    int idx = (blockIdx.x * 256 + threadIdx.x) * 4;
    float4 v = *(const float4*)&x[idx];
    float p[4] = { v.x, v.y, v.z, v.w };
    unsigned h01, h23, l01, l23;
    us h[4], l[4];
#pragma unroll
    for (int t = 0; t < 4; ++t) {
        h[t] = f2bf(p[t]);
        l[t] = f2bf(p[t] - bf2f(h[t]));
    }
    h01 = (unsigned)h[0] | ((unsigned)h[1] << 16);
    h23 = (unsigned)h[2] | ((unsigned)h[3] << 16);
    l01 = (unsigned)l[0] | ((unsigned)l[1] << 16);
    l23 = (unsigned)l[2] | ((unsigned)l[3] << 16);
    ((unsigned*)Xhi)[idx / 2]     = h01;
    ((unsigned*)Xhi)[idx / 2 + 1] = h23;
    ((unsigned*)Xlo)[idx / 2]     = l01;
    ((unsigned*)Xlo)[idx / 2 + 1] = l23;
}

// ------------------------------------------------ prep: W [k][o][d] -> Wt [d][o][k] split
__global__ void wprep_kernel(const float* __restrict__ W,
                             us* __restrict__ Wthi, us* __restrict__ Wtlo) {
    int idx = blockIdx.x * 256 + threadIdx.x;        // 262144 total
    int d  = idx & 3;
    int o  = (idx >> 2) & (OUT_SZ - 1);
    int kc = idx >> 12;                              // 0..63, 16 k each
    us h[16], l[16];
#pragma unroll
    for (int t = 0; t < 16; ++t) {
        float v = W[((size_t)(kc * 16 + t) * OUT_SZ + o) * 4 + d];
        h[t] = f2bf(v);
        l[t] = f2bf(v - bf2f(h[t]));
    }
    size_t base = (size_t)d * WPLANE + (size_t)o * OUT_SZ + kc * 16;
#pragma unroll
    for (int t = 0; t < 16; ++t) { Wthi[base + t] = h[t]; Wtlo[base + t] = l[t]; }
}

// pipeline sync helpers (rule #18: sched_barrier after inline-asm waitcnt)
__device__ __forceinline__ void wait_vm8() {
    asm volatile("s_waitcnt vmcnt(8)" ::: "memory");
    __builtin_amdgcn_sched_barrier(0);
}
__device__ __forceinline__ void wait_vm0() {
    asm volatile("s_waitcnt vmcnt(0)" ::: "memory");
    __builtin_amdgcn_sched_barrier(0);
}
__device__ __forceinline__ void wait_lgkm0() {
    asm volatile("s_waitcnt lgkmcnt(0)" ::: "memory");
    __builtin_amdgcn_sched_barrier(0);
}

// ------------------------------------------------ step: v' = norm(K' v + w)
// A = v (m=b), B = K' (n=i).  Block 64 b x 256 i, 8 waves (512 thr):
// wm = wv&1 -> 32-b half (bh=0,1), wn = wv>>1 -> 64-i quarter (nf=0..3).
// LDS frag = 512 shorts (64 lanes x 16B), lane-linear (DMA-compatible).
// A,B both double-buffered; depth-2 counted vmcnt(8); 2 barriers/iter.
__global__ __launch_bounds__(512, 2) void step_mfma_kernel(
    const us* __restrict__ Vhi, const us* __restrict__ Vlo,
    const us* __restrict__ Khi, const us* __restrict__ Klo,
    const float* __restrict__ omega,
    us* __restrict__ Ohi, us* __restrict__ Olo,
    float* __restrict__ out, int final_step)
{
    __shared__ short As[2][16384];  // v tile:  frag (d*4+bg)*2+hl  (32 KB/buf)
    __shared__ short Bs[2][16384];  // K' tile: frag ig*2+hl        (32 KB/buf)

    const int tid = threadIdx.x;
    const int ln = tid & 63, wv = tid >> 6;      // wv 0..7
    const int wm = wv & 1, wn = wv >> 1;

    // swizzle: 512 blocks, XCD = lid&7 gets contiguous n-chunk: per XCD
    // 16 b-tiles x 4 i-tiles; consecutive n = same b0, 4 i0 -> A L2-reuse;
    // K' i-columns (4 x 1MB) fully L2-resident per XCD.
    const int lid = blockIdx.y * 4 + blockIdx.x;          // 0..511
    const int n   = (lid & 7) * 64 + (lid >> 3);          // bijective
    const int i0 = (n & 3) * 256;
    const int b0 = (n >> 2) * 64;

    // 8 DMA frags per wave, unified list t = wv*8+j:
    // t<32: A-frag (d=t>>3, bg=(t>>1)&3, hl=t&1); t>=32: B-frag (ig,hl).
    const us* gsrc[8];
    short*    ldst[8];
#pragma unroll
    for (int j = 0; j < 8; ++j) {
        int t = wv * 8 + j;
        if (t < 32) {
            int d = t >> 3, bg = (t >> 1) & 3, hl = t & 1;
            int b = b0 + bg * 16 + (ln & 15);
            const us* base = hl ? Vlo : Vhi;
            gsrc[j] = base + (size_t)d * PLANE + (size_t)b * OUT_SZ + (ln >> 4) * 8;
            ldst[j] = &As[0][((d * 4 + bg) * 2 + hl) * 512];
        } else {
            int u = t - 32, ig = u >> 1, hl = u & 1;
            int i = i0 + ig * 16 + (ln & 15);
            const us* base = hl ? Klo : Khi;
            gsrc[j] = base + (size_t)i * OUT_SZ + (ln >> 4) * 8;
            ldst[j] = &Bs[0][(ig * 2 + hl) * 512];
        }
    }

    f32x4 acc[4][2][4];   // [d][bh][nf]
#pragma unroll
    for (int d = 0; d < 4; ++d)
#pragma unroll
        for (int bh = 0; bh < 2; ++bh)
#pragma unroll
            for (int nf = 0; nf < 4; ++nf) acc[d][bh][nf] = (f32x4){0.f, 0.f, 0.f, 0.f};

    // prologue: stage(0) -> buf0, stage(1) -> buf1 (16 outstanding per wave)
#pragma unroll
    for (int j = 0; j < 8; ++j) { dma16(gsrc[j], ldst[j]); gsrc[j] += 32; }
#pragma unroll
    for (int j = 0; j < 8; ++j) { dma16(gsrc[j], ldst[j] + 16384); gsrc[j] += 32; }

    int cur = 0;
    for (int it = 0; it < 32; ++it) {
        if (it < 31) wait_vm8(); else wait_vm0();   // own stage(it) landed
        __builtin_amdgcn_s_barrier();               // barrier A: buf[cur] ready

        short8 bfr[4][2];
#pragma unroll
        for (int nf = 0; nf < 4; ++nf)
#pragma unroll
            for (int hl = 0; hl < 2; ++hl)
                bfr[nf][hl] = *(const short8*)&Bs[cur][((wn * 4 + nf) * 2 + hl) * 512 + ln * 8];

#pragma unroll
        for (int bh = 0; bh < 2; ++bh) {
            const int bg = wm * 2 + bh;
            short8 afr[4][2];
#pragma unroll
            for (int d = 0; d < 4; ++d)
#pragma unroll
                for (int hl = 0; hl < 2; ++hl)
                    afr[d][hl] = *(const short8*)&As[cur][((d * 4 + bg) * 2 + hl) * 512 + ln * 8];

            // 3 passes x 16 independent MFMAs; per-acc order hh->lh->hl.
            __builtin_amdgcn_s_setprio(1);
#pragma unroll
            for (int d = 0; d < 4; ++d)
#pragma unroll
                for (int nf = 0; nf < 4; ++nf)
                    acc[d][bh][nf] = __builtin_amdgcn_mfma_f32_16x16x32_bf16(afr[d][0], bfr[nf][0], acc[d][bh][nf], 0, 0, 0);
#pragma unroll
            for (int d = 0; d < 4; ++d)
#pragma unroll
                for (int nf = 0; nf < 4; ++nf)
                    acc[d][bh][nf] = __builtin_amdgcn_mfma_f32_16x16x32_bf16(afr[d][1], bfr[nf][0], acc[d][bh][nf], 0, 0, 0);
#pragma unroll
            for (int d = 0; d < 4; ++d)
#pragma unroll
                for (int nf = 0; nf < 4; ++nf)
                    acc[d][bh][nf] = __builtin_amdgcn_mfma_f32_16x16x32_bf16(afr[d][0], bfr[nf][1], acc[d][bh][nf], 0, 0, 0);
            __builtin_amdgcn_s_setprio(0);
        }

        wait_lgkm0();                               // all my LDS reads retired
        __builtin_amdgcn_s_barrier();               // barrier B: safe to overwrite
        if (it + 2 < 32) {                          // stage(it+2) -> buf[cur]
#pragma unroll
            for (int j = 0; j < 8; ++j) {
                dma16(gsrc[j], ldst[j] + cur * 16384);
                gsrc[j] += 32;
            }
        }
        cur ^= 1;
    }

    // epilogue: C row = b, col = i (lane-contiguous stores)
#pragma unroll
    for (int bh = 0; bh < 2; ++bh)
#pragma unroll
        for (int nf = 0; nf < 4; ++nf) {
            const int i = i0 + wn * 64 + nf * 16 + (ln & 15);
            const f32x4 om = *(const f32x4*)&omega[i * 4];
#pragma unroll
            for (int reg = 0; reg < 4; ++reg) {
                const int b = b0 + wm * 32 + bh * 16 + (ln >> 4) * 4 + reg;
                float tv[4];
#pragma unroll
                for (int d = 0; d < 4; ++d) tv[d] = acc[d][bh][nf][reg] + om[d];
                float s = rnorm4(tv[0], tv[1], tv[2], tv[3]);
                if (final_step) {
                    f32x4 rr = { tv[0] * s, tv[1] * s, tv[2] * s, tv[3] * s };
                    *(f32x4*)&out[((size_t)b * OUT_SZ + i) * 4] = rr;
                } else {
#pragma unroll
                    for (int d = 0; d < 4; ++d) {
                        float val = tv[d] * s;
                        us hi = f2bf(val);
                        size_t idx = (size_t)d * PLANE + (size_t)b * OUT_SZ + i;
                        Ohi[idx] = hi;
                        Olo[idx] = f2bf(val - bf2f(hi));
                    }
                }
            }
        }
}

// ------------------------------------------------ init: v0 = norm(x @ W)
// A = x (m=b), B = Wt planes (n=o, per d).  Block 256 b x 64 o, 8 waves:
// wm = wv&3 -> 64-b slice (mf=0..3), wn = wv>>2 -> 32-o half (nf=0,1).
// Same dbuf + counted-vmcnt skeleton as the step kernel.
__global__ __launch_bounds__(512, 2) void init_mfma_kernel(
    const us* __restrict__ Xhi, const us* __restrict__ Xlo,
    const us* __restrict__ Wthi, const us* __restrict__ Wtlo,
    us* __restrict__ Ohi, us* __restrict__ Olo)
{
    __shared__ short As[2][16384];  // x tile:  frag bg*2+hl        (bg=0..15)
    __shared__ short Bs[2][16384];  // Wt tile: frag (d*4+og)*2+hl

    const int tid = threadIdx.x;
    const int ln = tid & 63, wv = tid >> 6;
    const int wm = wv & 3, wn = wv >> 2;

    // swizzle: per XCD fixed b-range (4 b-tiles) x all 16 o-tiles; consecutive
    // n = same o0, 4 b -> Wt-column L2-reuse.
    const int lid = blockIdx.y * 16 + blockIdx.x;         // 0..511
    const int n   = (lid & 7) * 64 + (lid >> 3);          // bijective
    const int o0 = ((n >> 2) & 15) * 64;
    const int b0 = ((n & 3) + ((n >> 6) << 2)) * 256;

    // 8 DMA frags per wave: t<32: A (bg=t>>1, hl=t&1); t>=32: B (d,og,hl).
    const us* gsrc[8];
    short*    ldst[8];
#pragma unroll
    for (int j = 0; j < 8; ++j) {
        int t = wv * 8 + j;
        if (t < 32) {
            int bg = t >> 1, hl = t & 1;
            int b = b0 + bg * 16 + (ln & 15);
            const us* base = hl ? Xlo : Xhi;
            gsrc[j] = base + (size_t)b * 1024 + (ln >> 4) * 8;
            ldst[j] = &As[0][(bg * 2 + hl) * 512];
        } else {
            int u = t - 32, d = u >> 3, og = (u >> 1) & 3, hl = u & 1;
            int o = o0 + og * 16 + (ln & 15);
            const us* base = hl ? Wtlo : Wthi;
            gsrc[j] = base + (size_t)d * WPLANE + (size_t)o * OUT_SZ + (ln >> 4) * 8;
            ldst[j] = &Bs[0][((d * 4 + og) * 2 + hl) * 512];
        }
    }

    f32x4 acc[4][4][2];   // [d][mf][nf]
#pragma unroll
    for (int d = 0; d < 4; ++d)
#pragma unroll
        for (int mf = 0; mf < 4; ++mf)
#pragma unroll
            for (int nf = 0; nf < 2; ++nf) acc[d][mf][nf] = (f32x4){0.f, 0.f, 0.f, 0.f};

    // prologue
#pragma unroll
    for (int j = 0; j < 8; ++j) { dma16(gsrc[j], ldst[j]); gsrc[j] += 32; }
#pragma unroll
    for (int j = 0; j < 8; ++j) { dma16(gsrc[j], ldst[j] + 16384); gsrc[j] += 32; }

    int cur = 0;
    for (int it = 0; it < 32; ++it) {
        if (it < 31) wait_vm8(); else wait_vm0();
        __builtin_amdgcn_s_barrier();               // barrier A

        short8 bfr[4][2][2];   // [d][nf][hl]
#pragma unroll
        for (int d = 0; d < 4; ++d)
#pragma unroll
            for (int nf = 0; nf < 2; ++nf)
#pragma unroll
                for (int hl = 0; hl < 2; ++hl)
                    bfr[d][nf][hl] = *(const short8*)&Bs[cur][((d * 4 + (wn * 2 + nf)) * 2 + hl) * 512 + ln * 8];

#pragma unroll
        for (int mf = 0; mf < 4; ++mf) {
            const int bg = wm * 4 + mf;
            short8 afr[2];
#pragma unroll
            for (int hl = 0; hl < 2; ++hl)
                afr[hl] = *(const short8*)&As[cur][(bg * 2 + hl) * 512 + ln * 8];

            __builtin_amdgcn_s_setprio(1);
#pragma unroll
            for (int d = 0; d < 4; ++d)
#pragma unroll
                for (int nf = 0; nf < 2; ++nf)
                    acc[d][mf][nf] = __builtin_amdgcn_mfma_f32_16x16x32_bf16(afr[0], bfr[d][nf][0], acc[d][mf][nf], 0, 0, 0);
#pragma unroll
            for (int d = 0; d < 4; ++d)
#pragma unroll
                for (int nf = 0; nf < 2; ++nf)
                    acc[d][mf][nf] = __builtin_amdgcn_mfma_f32_16x16x32_bf16(afr[1], bfr[d][nf][0], acc[d][mf][nf], 0, 0, 0);
#pragma unroll
            for (int d = 0; d < 4; ++d)
#pragma unroll
                for (int nf = 0; nf < 2; ++nf)
                    acc[d][mf][nf] = __builtin_amdgcn_mfma_f32_16x16x32_bf16(afr[0], bfr[d][nf][1], acc[d][mf][nf], 0, 0, 0);
            __builtin_amdgcn_s_setprio(0);
        }

        wait_lgkm0();
        __builtin_amdgcn_s_barrier();               // barrier B
        if (it + 2 < 32) {
#pragma unroll
            for (int j = 0; j < 8; ++j) {
                dma16(gsrc[j], ldst[j] + cur * 16384);
                gsrc[j] += 32;
            }
        }
        cur ^= 1;
    }

#pragma unroll
    for (int mf = 0; mf < 4; ++mf)
#pragma unroll
        for (int nf = 0; nf < 2; ++nf) {
            const int o = o0 + (wn * 2 + nf) * 16 + (ln & 15);
#pragma unroll
            for (int reg = 0; reg < 4; ++reg) {
                const int b = b0 + (wm * 4 + mf) * 16 + (ln >> 4) * 4 + reg;
                float tv[4];
#pragma unroll
                for (int d = 0; d < 4; ++d) tv[d] = acc[d][mf][nf][reg];
                float s = rnorm4(tv[0], tv[1], tv[2], tv[3]);
#pragma unroll
                for (int d = 0; d < 4; ++d) {
                    float val = tv[d] * s;
                    us hi = f2bf(val);
                    size_t idx = (size_t)d * PLANE + (size_t)b * OUT_SZ + o;
                    Ohi[idx] = hi;
                    Olo[idx] = f2bf(val - bf2f(hi));
                }
            }
        }
}

// ------------------------------------------------ launch
extern "C" void kernel_launch(void* const* d_in, const int* in_sizes, int n_in,
                              void* d_out, int out_size, void* d_ws, size_t ws_size,
                              hipStream_t stream) {
    const float* x        = (const float*)d_in[0];
    const float* W_in     = (const float*)d_in[1];
    const float* omega    = (const float*)d_in[2];
    const float* coupling = (const float*)d_in[3];
    float* out = (float*)d_out;

    us* Khi = (us*)d_ws;
    us* Klo = Khi + WPLANE;
    us* Ahi = Klo + WPLANE;          // ping planes (134 MB hi+lo)
    us* Alo = Ahi + 4 * PLANE;
    us* Bhi = (us*)d_out;            // pong planes alias d_out
    us* Blo = Bhi + 4 * PLANE;

    // prep scratch aliased into A region (init consumes before s0 overwrites)
    us* Xhi  = Ahi;
    us* Xlo  = Xhi + (size_t)B_SZ * 1024;
    us* Wthi = Xlo + (size_t)B_SZ * 1024;
    us* Wtlo = Wthi + 4 * WPLANE;

    tanhsplit_kernel<<<(OUT_SZ * OUT_SZ) / 256, 256, 0, stream>>>(coupling, Khi, Klo);
    xsplit_kernel<<<(B_SZ * 1024) / 1024, 256, 0, stream>>>(x, Xhi, Xlo);
    wprep_kernel<<<(4 * OUT_SZ * 64) / 256, 256, 0, stream>>>(W_in, Wthi, Wtlo);

    init_mfma_kernel<<<dim3(OUT_SZ / 64, B_SZ / 256), 512, 0, stream>>>(
        Xhi, Xlo, Wthi, Wtlo, Bhi, Blo);

    for (int s = 0; s < STEPS; ++s) {
        const us* Shi = (s & 1) ? Ahi : Bhi;
        const us* Slo = (s & 1) ? Alo : Blo;
        us*       Dhi = (s & 1) ? Bhi : Ahi;
        us*       Dlo = (s & 1) ? Blo : Alo;
        int fin = (s == STEPS - 1);
        step_mfma_kernel<<<dim3(OUT_SZ / 256, B_SZ / 64), 512, 0, stream>>>(
            Shi, Slo, Khi, Klo, omega, Dhi, Dlo, out, fin);
    }
}

// Round 8
// 2084.164 us; speedup vs baseline: 1.2764x; 1.0869x over previous
//
#include <hip/hip_runtime.h>
#include <math.h>

// AKOrN layer — split-bf16 MFMA, DMA staging, swapped operand roles.
//
// This revision (VMEM-path polish; model: wall ~= total VMEM bytes at
// ~10.5 B/cyc/CU):
//  * Morton 2x2 block ordering within each XCD's tile range: working window
//    2 A-tiles + 2 B-tiles = 4 MB = L2 (was 5 MB -> thrash).
//  * init inner loop restructured d-outer (12 live operand short8 vs 16
//    preloaded B-frags = 128 VGPR spike) — mirrors the faster step kernel.
//  * epilogue store order: nf innermost + omega preload, so the 4 stores
//    filling one 128-B line are adjacent in time (L2 write-combining; WRITE
//    was 1.9x logical).
//  * (kept) 64b x 256i step / 256b x 64o init tiles, 8 waves, 128 KB dbuf
//    LDS, depth-2 counted vmcnt(8), two raw barriers/iter, 3-pass MFMAs,
//    setprio. Bit-identical numerics (same per-acc order, same values).

#define B_SZ   8192
#define OUT_SZ 1024
#define STEPS  8
#define PLANE  ((size_t)B_SZ * OUT_SZ)
#define WPLANE ((size_t)OUT_SZ * OUT_SZ)

typedef __attribute__((ext_vector_type(8))) short  short8;
typedef __attribute__((ext_vector_type(4))) float  f32x4;
typedef unsigned short us;

__device__ __forceinline__ us f2bf(float f) {
    union { float f; unsigned u; } v; v.f = f;
    unsigned r = v.u + 0x7FFFu + ((v.u >> 16) & 1u);
    return (us)(r >> 16);
}
__device__ __forceinline__ float bf2f(us h) {
    union { unsigned u; float f; } v; v.u = ((unsigned)h) << 16;
    return v.f;
}
// async global->LDS, 16B per lane, dest = uniform base + lane*16
__device__ __forceinline__ void dma16(const void* g, void* l) {
    __builtin_amdgcn_global_load_lds(
        (const __attribute__((address_space(1))) void*)g,
        (__attribute__((address_space(3))) void*)l, 16, 0, 0);
}
__device__ __forceinline__ float rnorm4(float a, float b, float c, float d) {
    float n2 = a * a + b * b + c * c + d * d;
    float s = rsqrtf(fmaxf(n2, 1e-24f));
    return s * (1.5f - 0.5f * n2 * s * s);   // 1 NR step -> fp32 accuracy
}

// ------------------------------------------------ prep: K' = tanh(c)+I, split
__global__ void tanhsplit_kernel(const float* __restrict__ c,
                                 us* __restrict__ Khi, us* __restrict__ Klo) {
    int idx = blockIdx.x * 256 + threadIdx.x;
    float val = tanhf(c[idx]) + (((idx >> 10) == (idx & (OUT_SZ - 1))) ? 1.0f : 0.0f);
    us hi = f2bf(val);
    Khi[idx] = hi;
    Klo[idx] = f2bf(val - bf2f(hi));
}

// ------------------------------------------------ prep: split x -> bf16 hi/lo
__global__ void xsplit_kernel(const float* __restrict__ x,
                              us* __restrict__ Xhi, us* __restrict__ Xlo) {
    int idx = (blockIdx.x * 256 + threadIdx.x) * 4;
    float4 v = *(const float4*)&x[idx];
    float p[4] = { v.x, v.y, v.z, v.w };
    unsigned h01, h23, l01, l23;
    us h[4], l[4];
#pragma unroll
    for (int t = 0; t < 4; ++t) {
        h[t] = f2bf(p[t]);
        l[t] = f2bf(p[t] - bf2f(h[t]));
    }
    h01 = (unsigned)h[0] | ((unsigned)h[1] << 16);
    h23 = (unsigned)h[2] | ((unsigned)h[3] << 16);
    l01 = (unsigned)l[0] | ((unsigned)l[1] << 16);
    l23 = (unsigned)l[2] | ((unsigned)l[3] << 16);
    ((unsigned*)Xhi)[idx / 2]     = h01;
    ((unsigned*)Xhi)[idx / 2 + 1] = h23;
    ((unsigned*)Xlo)[idx / 2]     = l01;
    ((unsigned*)Xlo)[idx / 2 + 1] = l23;
}

// ------------------------------------------------ prep: W [k][o][d] -> Wt [d][o][k] split
__global__ void wprep_kernel(const float* __restrict__ W,
                             us* __restrict__ Wthi, us* __restrict__ Wtlo) {
    int idx = blockIdx.x * 256 + threadIdx.x;        // 262144 total
    int d  = idx & 3;
    int o  = (idx >> 2) & (OUT_SZ - 1);
    int kc = idx >> 12;                              // 0..63, 16 k each
    us h[16], l[16];
#pragma unroll
    for (int t = 0; t < 16; ++t) {
        float v = W[((size_t)(kc * 16 + t) * OUT_SZ + o) * 4 + d];
        h[t] = f2bf(v);
        l[t] = f2bf(v - bf2f(h[t]));
    }
    size_t base = (size_t)d * WPLANE + (size_t)o * OUT_SZ + kc * 16;
#pragma unroll
    for (int t = 0; t < 16; ++t) { Wthi[base + t] = h[t]; Wtlo[base + t] = l[t]; }
}

// pipeline sync helpers (rule #18: sched_barrier after inline-asm waitcnt)
__device__ __forceinline__ void wait_vm8() {
    asm volatile("s_waitcnt vmcnt(8)" ::: "memory");
    __builtin_amdgcn_sched_barrier(0);
}
__device__ __forceinline__ void wait_vm0() {
    asm volatile("s_waitcnt vmcnt(0)" ::: "memory");
    __builtin_amdgcn_sched_barrier(0);
}
__device__ __forceinline__ void wait_lgkm0() {
    asm volatile("s_waitcnt lgkmcnt(0)" ::: "memory");
    __builtin_amdgcn_sched_barrier(0);
}

// ------------------------------------------------ step: v' = norm(K' v + w)
// A = v (m=b), B = K' (n=i).  Block 64 b x 256 i, 8 waves (512 thr):
// wm = wv&1 -> 32-b half (bh=0,1), wn = wv>>1 -> 64-i quarter (nf=0..3).
__global__ __launch_bounds__(512, 2) void step_mfma_kernel(
    const us* __restrict__ Vhi, const us* __restrict__ Vlo,
    const us* __restrict__ Khi, const us* __restrict__ Klo,
    const float* __restrict__ omega,
    us* __restrict__ Ohi, us* __restrict__ Olo,
    float* __restrict__ out, int final_step)
{
    __shared__ short As[2][16384];  // v tile:  frag (d*4+bg)*2+hl  (32 KB/buf)
    __shared__ short Bs[2][16384];  // K' tile: frag ig*2+hl        (32 KB/buf)

    const int tid = threadIdx.x;
    const int ln = tid & 63, wv = tid >> 6;      // wv 0..7
    const int wm = wv & 1, wn = wv >> 1;

    // XCD = lid&7 owns 16 b-tiles x 4 i-tiles; Morton 2x2 within:
    // working window = 2 V-tiles (2 MB) + 2 K' columns (2 MB) = 4 MB = L2.
    const int lid = blockIdx.y * 4 + blockIdx.x;          // 0..511
    const int X   = lid & 7, nn = lid >> 3;               // nn 0..63
    const int i_idx = (nn & 1) | (((nn >> 2) & 1) << 1);                       // 2 bits
    const int b_idx = ((nn >> 1) & 1) | (((nn >> 3) & 1) << 1) | (((nn >> 4) & 3) << 2); // 4 bits
    const int i0 = i_idx * 256;
    const int b0 = (X * 16 + b_idx) * 64;

    // 8 DMA frags per wave, unified list t = wv*8+j:
    // t<32: A-frag (d=t>>3, bg=(t>>1)&3, hl=t&1); t>=32: B-frag (ig,hl).
    const us* gsrc[8];
    short*    ldst[8];
#pragma unroll
    for (int j = 0; j < 8; ++j) {
        int t = wv * 8 + j;
        if (t < 32) {
            int d = t >> 3, bg = (t >> 1) & 3, hl = t & 1;
            int b = b0 + bg * 16 + (ln & 15);
            const us* base = hl ? Vlo : Vhi;
            gsrc[j] = base + (size_t)d * PLANE + (size_t)b * OUT_SZ + (ln >> 4) * 8;
            ldst[j] = &As[0][((d * 4 + bg) * 2 + hl) * 512];
        } else {
            int u = t - 32, ig = u >> 1, hl = u & 1;
            int i = i0 + ig * 16 + (ln & 15);
            const us* base = hl ? Klo : Khi;
            gsrc[j] = base + (size_t)i * OUT_SZ + (ln >> 4) * 8;
            ldst[j] = &Bs[0][(ig * 2 + hl) * 512];
        }
    }

    f32x4 acc[4][2][4];   // [d][bh][nf]
#pragma unroll
    for (int d = 0; d < 4; ++d)
#pragma unroll
        for (int bh = 0; bh < 2; ++bh)
#pragma unroll
            for (int nf = 0; nf < 4; ++nf) acc[d][bh][nf] = (f32x4){0.f, 0.f, 0.f, 0.f};

    // prologue: stage(0) -> buf0, stage(1) -> buf1 (16 outstanding per wave)
#pragma unroll
    for (int j = 0; j < 8; ++j) { dma16(gsrc[j], ldst[j]); gsrc[j] += 32; }
#pragma unroll
    for (int j = 0; j < 8; ++j) { dma16(gsrc[j], ldst[j] + 16384); gsrc[j] += 32; }

    int cur = 0;
    for (int it = 0; it < 32; ++it) {
        if (it < 31) wait_vm8(); else wait_vm0();   // own stage(it) landed
        __builtin_amdgcn_s_barrier();               // barrier A: buf[cur] ready

        short8 bfr[4][2];
#pragma unroll
        for (int nf = 0; nf < 4; ++nf)
#pragma unroll
            for (int hl = 0; hl < 2; ++hl)
                bfr[nf][hl] = *(const short8*)&Bs[cur][((wn * 4 + nf) * 2 + hl) * 512 + ln * 8];

#pragma unroll
        for (int bh = 0; bh < 2; ++bh) {
            const int bg = wm * 2 + bh;
            short8 afr[4][2];
#pragma unroll
            for (int d = 0; d < 4; ++d)
#pragma unroll
                for (int hl = 0; hl < 2; ++hl)
                    afr[d][hl] = *(const short8*)&As[cur][((d * 4 + bg) * 2 + hl) * 512 + ln * 8];

            // 3 passes x 16 independent MFMAs; per-acc order hh->lh->hl.
            __builtin_amdgcn_s_setprio(1);
#pragma unroll
            for (int d = 0; d < 4; ++d)
#pragma unroll
                for (int nf = 0; nf < 4; ++nf)
                    acc[d][bh][nf] = __builtin_amdgcn_mfma_f32_16x16x32_bf16(afr[d][0], bfr[nf][0], acc[d][bh][nf], 0, 0, 0);
#pragma unroll
            for (int d = 0; d < 4; ++d)
#pragma unroll
                for (int nf = 0; nf < 4; ++nf)
                    acc[d][bh][nf] = __builtin_amdgcn_mfma_f32_16x16x32_bf16(afr[d][1], bfr[nf][0], acc[d][bh][nf], 0, 0, 0);
#pragma unroll
            for (int d = 0; d < 4; ++d)
#pragma unroll
                for (int nf = 0; nf < 4; ++nf)
                    acc[d][bh][nf] = __builtin_amdgcn_mfma_f32_16x16x32_bf16(afr[d][0], bfr[nf][1], acc[d][bh][nf], 0, 0, 0);
            __builtin_amdgcn_s_setprio(0);
        }

        wait_lgkm0();                               // all my LDS reads retired
        __builtin_amdgcn_s_barrier();               // barrier B: safe to overwrite
        if (it + 2 < 32) {                          // stage(it+2) -> buf[cur]
#pragma unroll
            for (int j = 0; j < 8; ++j) {
                dma16(gsrc[j], ldst[j] + cur * 16384);
                gsrc[j] += 32;
            }
        }
        cur ^= 1;
    }

    // epilogue: nf innermost so the 4 stores filling one 128-B line are
    // adjacent in time (write-combining). Values identical to before.
    f32x4 om[4];
#pragma unroll
    for (int nf = 0; nf < 4; ++nf)
        om[nf] = *(const f32x4*)&omega[(i0 + wn * 64 + nf * 16 + (ln & 15)) * 4];

#pragma unroll
    for (int bh = 0; bh < 2; ++bh)
#pragma unroll
        for (int reg = 0; reg < 4; ++reg) {
            const int b = b0 + wm * 32 + bh * 16 + (ln >> 4) * 4 + reg;
#pragma unroll
            for (int nf = 0; nf < 4; ++nf) {
                const int i = i0 + wn * 64 + nf * 16 + (ln & 15);
                float tv[4];
#pragma unroll
                for (int d = 0; d < 4; ++d) tv[d] = acc[d][bh][nf][reg] + om[nf][d];
                float s = rnorm4(tv[0], tv[1], tv[2], tv[3]);
                if (final_step) {
                    f32x4 rr = { tv[0] * s, tv[1] * s, tv[2] * s, tv[3] * s };
                    *(f32x4*)&out[((size_t)b * OUT_SZ + i) * 4] = rr;
                } else {
#pragma unroll
                    for (int d = 0; d < 4; ++d) {
                        float val = tv[d] * s;
                        us hi = f2bf(val);
                        size_t idx = (size_t)d * PLANE + (size_t)b * OUT_SZ + i;
                        Ohi[idx] = hi;
                        Olo[idx] = f2bf(val - bf2f(hi));
                    }
                }
            }
        }
}

// ------------------------------------------------ init: v0 = norm(x @ W)
// A = x (m=b), B = Wt planes (n=o, per d).  Block 256 b x 64 o, 8 waves:
// wm = wv&3 -> 64-b slice (mf=0..3), wn = wv>>2 -> 32-o half (nf=0,1).
__global__ __launch_bounds__(512, 2) void init_mfma_kernel(
    const us* __restrict__ Xhi, const us* __restrict__ Xlo,
    const us* __restrict__ Wthi, const us* __restrict__ Wtlo,
    us* __restrict__ Ohi, us* __restrict__ Olo)
{
    __shared__ short As[2][16384];  // x tile:  frag bg*2+hl        (bg=0..15)
    __shared__ short Bs[2][16384];  // Wt tile: frag (d*4+og)*2+hl

    const int tid = threadIdx.x;
    const int ln = tid & 63, wv = tid >> 6;
    const int wm = wv & 3, wn = wv >> 2;

    // XCD owns 4 b-tiles x 16 o-tiles; Morton 2x2 within:
    // window = 2 x-tiles (2 MB) + 2 Wt o-tiles (2 MB) = 4 MB = L2.
    const int lid = blockIdx.y * 16 + blockIdx.x;         // 0..511
    const int X   = lid & 7, nn = lid >> 3;               // nn 0..63
    const int o_idx = (nn & 1) | (((nn >> 2) & 1) << 1) | (((nn >> 4) & 3) << 2); // 4 bits
    const int b_idx = ((nn >> 1) & 1) | (((nn >> 3) & 1) << 1);                   // 2 bits
    const int o0 = o_idx * 64;
    const int b0 = (X * 4 + b_idx) * 256;

    // 8 DMA frags per wave: t<32: A (bg=t>>1, hl=t&1); t>=32: B (d,og,hl).
    const us* gsrc[8];
    short*    ldst[8];
#pragma unroll
    for (int j = 0; j < 8; ++j) {
        int t = wv * 8 + j;
        if (t < 32) {
            int bg = t >> 1, hl = t & 1;
            int b = b0 + bg * 16 + (ln & 15);
            const us* base = hl ? Xlo : Xhi;
            gsrc[j] = base + (size_t)b * 1024 + (ln >> 4) * 8;
            ldst[j] = &As[0][(bg * 2 + hl) * 512];
        } else {
            int u = t - 32, d = u >> 3, og = (u >> 1) & 3, hl = u & 1;
            int o = o0 + og * 16 + (ln & 15);
            const us* base = hl ? Wtlo : Wthi;
            gsrc[j] = base + (size_t)d * WPLANE + (size_t)o * OUT_SZ + (ln >> 4) * 8;
            ldst[j] = &Bs[0][((d * 4 + og) * 2 + hl) * 512];
        }
    }

    f32x4 acc[4][4][2];   // [d][mf][nf]
#pragma unroll
    for (int d = 0; d < 4; ++d)
#pragma unroll
        for (int mf = 0; mf < 4; ++mf)
#pragma unroll
            for (int nf = 0; nf < 2; ++nf) acc[d][mf][nf] = (f32x4){0.f, 0.f, 0.f, 0.f};

    // prologue
#pragma unroll
    for (int j = 0; j < 8; ++j) { dma16(gsrc[j], ldst[j]); gsrc[j] += 32; }
#pragma unroll
    for (int j = 0; j < 8; ++j) { dma16(gsrc[j], ldst[j] + 16384); gsrc[j] += 32; }

    int cur = 0;
    for (int it = 0; it < 32; ++it) {
        if (it < 31) wait_vm8(); else wait_vm0();
        __builtin_amdgcn_s_barrier();               // barrier A

        // d-outer: 12 live operand short8 (48 VGPR) vs 16-preload spike.
#pragma unroll
        for (int d = 0; d < 4; ++d) {
            short8 bfr[2][2];
#pragma unroll
            for (int nf = 0; nf < 2; ++nf)
#pragma unroll
                for (int hl = 0; hl < 2; ++hl)
                    bfr[nf][hl] = *(const short8*)&Bs[cur][((d * 4 + (wn * 2 + nf)) * 2 + hl) * 512 + ln * 8];
            short8 afr[4][2];
#pragma unroll
            for (int mf = 0; mf < 4; ++mf)
#pragma unroll
                for (int hl = 0; hl < 2; ++hl)
                    afr[mf][hl] = *(const short8*)&As[cur][((wm * 4 + mf) * 2 + hl) * 512 + ln * 8];

            __builtin_amdgcn_s_setprio(1);
#pragma unroll
            for (int mf = 0; mf < 4; ++mf)
#pragma unroll
                for (int nf = 0; nf < 2; ++nf)
                    acc[d][mf][nf] = __builtin_amdgcn_mfma_f32_16x16x32_bf16(afr[mf][0], bfr[nf][0], acc[d][mf][nf], 0, 0, 0);
#pragma unroll
            for (int mf = 0; mf < 4; ++mf)
#pragma unroll
                for (int nf = 0; nf < 2; ++nf)
                    acc[d][mf][nf] = __builtin_amdgcn_mfma_f32_16x16x32_bf16(afr[mf][1], bfr[nf][0], acc[d][mf][nf], 0, 0, 0);
#pragma unroll
            for (int mf = 0; mf < 4; ++mf)
#pragma unroll
                for (int nf = 0; nf < 2; ++nf)
                    acc[d][mf][nf] = __builtin_amdgcn_mfma_f32_16x16x32_bf16(afr[mf][0], bfr[nf][1], acc[d][mf][nf], 0, 0, 0);
            __builtin_amdgcn_s_setprio(0);
        }

        wait_lgkm0();
        __builtin_amdgcn_s_barrier();               // barrier B
        if (it + 2 < 32) {
#pragma unroll
            for (int j = 0; j < 8; ++j) {
                dma16(gsrc[j], ldst[j] + cur * 16384);
                gsrc[j] += 32;
            }
        }
        cur ^= 1;
    }

    // epilogue: nf innermost (adjacent-in-time same-line stores).
#pragma unroll
    for (int mf = 0; mf < 4; ++mf)
#pragma unroll
        for (int reg = 0; reg < 4; ++reg) {
            const int b = b0 + (wm * 4 + mf) * 16 + (ln >> 4) * 4 + reg;
#pragma unroll
            for (int nf = 0; nf < 2; ++nf) {
                const int o = o0 + (wn * 2 + nf) * 16 + (ln & 15);
                float tv[4];
#pragma unroll
                for (int d = 0; d < 4; ++d) tv[d] = acc[d][mf][nf][reg];
                float s = rnorm4(tv[0], tv[1], tv[2], tv[3]);
#pragma unroll
                for (int d = 0; d < 4; ++d) {
                    float val = tv[d] * s;
                    us hi = f2bf(val);
                    size_t idx = (size_t)d * PLANE + (size_t)b * OUT_SZ + o;
                    Ohi[idx] = hi;
                    Olo[idx] = f2bf(val - bf2f(hi));
                }
            }
        }
}

// ------------------------------------------------ launch
extern "C" void kernel_launch(void* const* d_in, const int* in_sizes, int n_in,
                              void* d_out, int out_size, void* d_ws, size_t ws_size,
                              hipStream_t stream) {
    const float* x        = (const float*)d_in[0];
    const float* W_in     = (const float*)d_in[1];
    const float* omega    = (const float*)d_in[2];
    const float* coupling = (const float*)d_in[3];
    float* out = (float*)d_out;

    us* Khi = (us*)d_ws;
    us* Klo = Khi + WPLANE;
    us* Ahi = Klo + WPLANE;          // ping planes (134 MB hi+lo)
    us* Alo = Ahi + 4 * PLANE;
    us* Bhi = (us*)d_out;            // pong planes alias d_out
    us* Blo = Bhi + 4 * PLANE;

    // prep scratch aliased into A region (init consumes before s0 overwrites)
    us* Xhi  = Ahi;
    us* Xlo  = Xhi + (size_t)B_SZ * 1024;
    us* Wthi = Xlo + (size_t)B_SZ * 1024;
    us* Wtlo = Wthi + 4 * WPLANE;

    tanhsplit_kernel<<<(OUT_SZ * OUT_SZ) / 256, 256, 0, stream>>>(coupling, Khi, Klo);
    xsplit_kernel<<<(B_SZ * 1024) / 1024, 256, 0, stream>>>(x, Xhi, Xlo);
    wprep_kernel<<<(4 * OUT_SZ * 64) / 256, 256, 0, stream>>>(W_in, Wthi, Wtlo);

    init_mfma_kernel<<<dim3(OUT_SZ / 64, B_SZ / 256), 512, 0, stream>>>(
        Xhi, Xlo, Wthi, Wtlo, Bhi, Blo);

    for (int s = 0; s < STEPS; ++s) {
        const us* Shi = (s & 1) ? Ahi : Bhi;
        const us* Slo = (s & 1) ? Alo : Blo;
        us*       Dhi = (s & 1) ? Bhi : Ahi;
        us*       Dlo = (s & 1) ? Blo : Alo;
        int fin = (s == STEPS - 1);
        step_mfma_kernel<<<dim3(OUT_SZ / 256, B_SZ / 64), 512, 0, stream>>>(
            Shi, Slo, Khi, Klo, omega, Dhi, Dlo, out, fin);
    }
}